// Round 1
// baseline (504.760 us; speedup 1.0000x reference)
//
#include <hip/hip_runtime.h>
#include <math.h>

#define NB 1024
#define NC 63
#define NF 250
#define NH 4
#define ND 250
#define NHD 1000

// ============================================================================
// Kernel A: per-batch normalize + 63x63 gram partials.
// grid 256 x 512 threads; each block accumulates 4 batches in registers
// (8x8 per-thread tile of the full 64x64-padded adj), writes one partial.
// LDS layout: xn stored TRANSPOSED xsT[f][64] so dot-phase reads are
// contiguous float4 along c (2-way bank aliasing only => free).
// ============================================================================
__global__ __launch_bounds__(512) void k_adj_partial(const float* __restrict__ x,
                                                     float* __restrict__ partial) {
    __shared__ __align__(16) float smem[16384];  // xsT[250][64] (16000) / red[8][64][32]
    __shared__ float psum[8][64], pss[8][64];
    __shared__ float meanv[64], sclv[64];
    const int t = threadIdx.x;
    const int lane = t & 63;   // c (load) / tile (dot)
    const int g = t >> 6;      // fgroup == wave id, 0..7
    const int f0 = g * 32;
    const int f1 = (f0 + 32 < NF) ? f0 + 32 : NF;
    const int tr = (lane >> 3) * 8;   // c-tile base
    const int tc = (lane & 7) * 8;    // d-tile base

    float acc[64];
#pragma unroll
    for (int a = 0; a < 64; ++a) acc[a] = 0.f;

    for (int bb = 0; bb < 4; ++bb) {
        const int b = blockIdx.x * 4 + bb;
        const float* xb = x + (size_t)b * (NC * NF);
        // phase 1: raw transposed load + per-(row,fgroup) moments
        float s = 0.f, ss = 0.f;
        if (lane < NC) {
            for (int f = f0; f < f1; ++f) {
                float v = xb[lane * NF + f];
                s += v; ss += v * v;
                smem[f * 64 + lane] = v;
            }
        } else {
            for (int f = f0; f < f1; ++f) smem[f * 64 + 63] = 0.f;
        }
        psum[g][lane] = s; pss[g][lane] = ss;
        __syncthreads();
        // phase 2: finalize mean / 1/(std_ddof1 + 1e-8)
        if (t < 64) {
            float S = 0.f, SS = 0.f;
#pragma unroll
            for (int gg = 0; gg < 8; ++gg) { S += psum[gg][t]; SS += pss[gg][t]; }
            float m = S / (float)NF;
            float var = (SS - S * S / (float)NF) / (float)(NF - 1);
            float sc = 1.f / (sqrtf(var) + 1e-8f);
            if (t >= NC) { m = 0.f; sc = 0.f; }   // keep pad column zero
            meanv[t] = m; sclv[t] = sc;
        }
        __syncthreads();
        // phase 3: normalize in place
        if (lane < NC) {
            const float m = meanv[lane], sc = sclv[lane];
            for (int f = f0; f < f1; ++f)
                smem[f * 64 + lane] = (smem[f * 64 + lane] - m) * sc;
        }
        __syncthreads();
        // phase 4: 8x8 register-tile outer products over this wave's f-range
        for (int f = f0; f < f1; ++f) {
            const float4 a0 = *(const float4*)&smem[f * 64 + tr];
            const float4 a1 = *(const float4*)&smem[f * 64 + tr + 4];
            const float4 b0 = *(const float4*)&smem[f * 64 + tc];
            const float4 b1 = *(const float4*)&smem[f * 64 + tc + 4];
            const float av[8] = {a0.x,a0.y,a0.z,a0.w,a1.x,a1.y,a1.z,a1.w};
            const float bv[8] = {b0.x,b0.y,b0.z,b0.w,b1.x,b1.y,b1.z,b1.w};
#pragma unroll
            for (int i = 0; i < 8; ++i)
#pragma unroll
                for (int j = 0; j < 8; ++j)
                    acc[i * 8 + j] += av[i] * bv[j];
        }
        __syncthreads();
    }
    // reduce the 8 fgroup copies (rotation-swizzled to avoid same-bank writes)
    float* red = smem;
#pragma unroll
    for (int half = 0; half < 2; ++half) {
        __syncthreads();
#pragma unroll
        for (int j = 0; j < 32; ++j)
            red[g * 2048 + lane * 32 + ((j + lane) & 31)] = acc[half * 32 + j];
        __syncthreads();
        for (int k = 0; k < 4; ++k) {
            int e = t + k * 512;             // 0..2047
            int tl = e >> 5, jp = e & 31;
            float sum = 0.f;
#pragma unroll
            for (int gg = 0; gg < 8; ++gg)
                sum += red[gg * 2048 + tl * 32 + ((jp + tl) & 31)];
            int a = half * 32 + jp;
            int row = (tl >> 3) * 8 + (a >> 3);
            int col = (tl & 7) * 8 + (a & 7);
            if (row < NC && col < NC)
                partial[(size_t)blockIdx.x * 4096 + row * 64 + col] = sum;
        }
    }
}

// ============================================================================
// Reduce 256 partials -> adj (63x63), scaled by 1/(F*B)
// ============================================================================
__global__ void k_adj_reduce(const float* __restrict__ partial, float* __restrict__ adj) {
    int e = blockIdx.x * 256 + threadIdx.x;
    if (e >= NC * NC) return;
    int row = e / NC, col = e % NC;
    float s = 0.f;
    for (int blk = 0; blk < 256; ++blk)
        s += partial[(size_t)blk * 4096 + row * 64 + col];
    adj[e] = s * (1.f / ((float)NF * (float)NB));
}

// ============================================================================
// Per-row 8th-largest (duplicate-aware) threshold + mask_full
// ============================================================================
__global__ void k_thresh_mask(const float* __restrict__ adj, float* __restrict__ thresh,
                              float* __restrict__ maskf) {
    int t = threadIdx.x;
    if (t < NC) {
        float prev = INFINITY;
        int krem = 8;                       // TOP_K
        float th = -INFINITY;
        for (int iter = 0; iter < 8; ++iter) {
            float vmax = -INFINITY; int cnt = 0;
            for (int j = 0; j < NC; ++j) {
                float v = adj[t * NC + j];
                if (v < prev) {
                    if (v > vmax) { vmax = v; cnt = 1; }
                    else if (v == vmax) cnt++;
                }
            }
            if (cnt >= krem) { th = vmax; break; }
            krem -= cnt; prev = vmax;
        }
        thresh[t] = th;
    }
    __syncthreads();
    for (int e = t; e < NC * NC; e += 256) {
        int i = e / NC, j = e % NC;
        float v = adj[e];
        bool m = (i == j) || ((v >= thresh[i]) && (v != 0.f));
        maskf[e] = m ? 1.f : 0.f;
    }
}

// ============================================================================
// h0 = x[0] @ W_gat   (63 x 1000)
// ============================================================================
__global__ __launch_bounds__(256) void k_h0(const float* __restrict__ x,
                                            const float* __restrict__ Wg,
                                            float* __restrict__ h0) {
    __shared__ float xrow[NF];
    int c = blockIdx.x, t = threadIdx.x;
    if (t < NF) xrow[t] = x[c * NF + t];
    __syncthreads();
    int n0 = t, n1 = t + 256, n2 = t + 512;
    int n3 = (t + 768 < NHD) ? t + 768 : NHD - 1;   // clamp, store guarded
    float acc0 = 0, acc1 = 0, acc2 = 0, acc3 = 0;
    for (int f = 0; f < NF; ++f) {
        float xv = xrow[f];
        const float* wr = Wg + (size_t)f * NHD;
        acc0 += xv * wr[n0];
        acc1 += xv * wr[n1];
        acc2 += xv * wr[n2];
        acc3 += xv * wr[n3];
    }
    h0[c * NHD + n0] = acc0;
    h0[c * NHD + n1] = acc1;
    h0[c * NHD + n2] = acc2;
    if (t + 768 < NHD) h0[c * NHD + n3] = acc3;
}

// ============================================================================
// a_s[c,h], a_d[c,h]
// ============================================================================
__global__ void k_asad(const float* __restrict__ h0, const float* __restrict__ att_src,
                       const float* __restrict__ att_dst, float* __restrict__ as_,
                       float* __restrict__ ad_) {
    int t = threadIdx.x;
    if (t >= NC * NH) return;
    int c = t >> 2, h = t & 3;
    const float* hr = h0 + c * NHD + h * ND;
    const float* sp = att_src + h * ND;
    const float* dp = att_dst + h * ND;
    float s0 = 0.f, s1 = 0.f;
    for (int dd = 0; dd < ND; ++dd) { s0 += hr[dd] * sp[dd]; s1 += hr[dd] * dp[dd]; }
    as_[t] = s0; ad_[t] = s1;
}

// ============================================================================
// w[i,j,h] = softmax over i of masked leaky_relu(a_s[i,h]+a_d[j,h])
// ============================================================================
__global__ void k_soft(const float* __restrict__ maskf, const float* __restrict__ as_,
                       const float* __restrict__ ad_, float* __restrict__ w) {
    int t = threadIdx.x;
    if (t >= NC * NH) return;
    int j = t >> 2, h = t & 3;
    float adv = ad_[j * 4 + h];
    float m = -INFINITY;
    for (int i = 0; i < NC; ++i) {
        if (maskf[i * NC + j] != 0.f) {
            float e = as_[i * 4 + h] + adv;
            e = e > 0.f ? e : 0.2f * e;
            m = fmaxf(m, e);
        }
    }
    float ssum = 0.f;
    for (int i = 0; i < NC; ++i) {
        float wv = 0.f;
        if (maskf[i * NC + j] != 0.f) {
            float e = as_[i * 4 + h] + adv;
            e = e > 0.f ? e : 0.2f * e;
            wv = expf(e - m);
            ssum += wv;
        }
        w[(i * NC + j) * 4 + h] = wv;
    }
    float inv = 1.f / ssum;
    for (int i = 0; i < NC; ++i)
        w[(i * NC + j) * 4 + h] *= inv;
}

// ============================================================================
// b=0 rows: att0[j] = sum_i w[i,j,h]*h0[i]; out0 = (att0+bias_gat)@W_proj+b_proj
// ============================================================================
__global__ __launch_bounds__(256) void k_out0(const float* __restrict__ w,
                                              const float* __restrict__ h0,
                                              const float* __restrict__ bias_gat,
                                              const float* __restrict__ Wp,
                                              const float* __restrict__ b_proj,
                                              float* __restrict__ out) {
    __shared__ float wcol[NC * NH];
    __shared__ float y[NHD];
    int j = blockIdx.x, t = threadIdx.x;
    if (t < NC * NH) {
        int i = t >> 2, h = t & 3;
        wcol[t] = w[(i * NC + j) * 4 + h];
    }
    __syncthreads();
    for (int n = t; n < NHD; n += 256) {
        int h = n / ND;
        float acc = 0.f;
        for (int i = 0; i < NC; ++i)
            acc += wcol[i * 4 + h] * h0[i * NHD + n];
        y[n] = acc + bias_gat[n];
    }
    __syncthreads();
    if (t < ND) {
        float acc = 0.f;
        for (int k = 0; k < NHD; ++k)
            acc += y[k] * Wp[k * ND + t];
        out[j * ND + t] = acc + b_proj[t];
    }
}

// ============================================================================
// Wc = W_gat @ W_proj (250x250), biasc = bias_gat @ W_proj + b_proj
// grid 126: blocks 0..124 do 2 Wc rows each; block 125 does biasc.
// ============================================================================
__global__ __launch_bounds__(256) void k_wc(const float* __restrict__ Wg,
                                            const float* __restrict__ bias_gat,
                                            const float* __restrict__ Wp,
                                            const float* __restrict__ b_proj,
                                            float* __restrict__ Wc,
                                            float* __restrict__ biasc) {
    __shared__ float rows[2 * NHD];
    int blk = blockIdx.x, t = threadIdx.x;
    if (blk < 125) {
        int fb = blk * 2;
        for (int idx = t; idx < 2 * NHD; idx += 256)
            rows[idx] = Wg[(size_t)fb * NHD + idx];   // two rows are contiguous
        __syncthreads();
        if (t < ND) {
            float a0 = 0.f, a1 = 0.f;
            for (int k = 0; k < NHD; ++k) {
                float wv = Wp[k * ND + t];
                a0 += rows[k] * wv;
                a1 += rows[NHD + k] * wv;
            }
            Wc[fb * ND + t] = a0;
            Wc[(fb + 1) * ND + t] = a1;
        }
    } else {
        for (int idx = t; idx < NHD; idx += 256) rows[idx] = bias_gat[idx];
        __syncthreads();
        if (t < ND) {
            float a0 = 0.f;
            for (int k = 0; k < NHD; ++k) a0 += rows[k] * Wp[k * ND + t];
            biasc[t] = a0 + b_proj[t];
        }
    }
}

// ============================================================================
// MAIN: out[row,:] = x[row,:] @ Wc + biasc  for all 64512 rows
// 64x256 tile per 256-thread block, K-chunks of 32, 8x8 per-thread micro-tile.
// b=0 rows get overwritten by k_out0 afterwards.
// ============================================================================
__global__ __launch_bounds__(256) void k_main(const float* __restrict__ x,
                                              const float* __restrict__ Wc,
                                              const float* __restrict__ biasc,
                                              float* __restrict__ out) {
    __shared__ float Xs[64][32];
    __shared__ float Ws[32][256];
    const int t = threadIdx.x;
    const int tx = t & 31, ty = t >> 5;
    const size_t m0 = (size_t)blockIdx.x * 64;
    float acc[64];
#pragma unroll
    for (int a = 0; a < 64; ++a) acc[a] = 0.f;

    for (int kc = 0; kc < 8; ++kc) {
        const int k0 = kc * 32;
        const int kl = (k0 + 32 <= NF) ? 32 : (NF - k0);
#pragma unroll
        for (int it = 0; it < 8; ++it) {
            int idx = t + it * 256;
            int r = idx >> 5, kk = idx & 31;
            Xs[r][kk] = (kk < kl) ? x[(m0 + r) * NF + k0 + kk] : 0.f;
        }
#pragma unroll
        for (int it = 0; it < 32; ++it) {
            int idx = t + it * 256;
            int k = idx >> 8, n = idx & 255;
            Ws[k][n] = (k < kl && n < ND) ? Wc[(size_t)(k0 + k) * ND + n] : 0.f;
        }
        __syncthreads();
#pragma unroll 8
        for (int kk = 0; kk < 32; ++kk) {
            float av[8], bv[8];
#pragma unroll
            for (int i = 0; i < 8; ++i) av[i] = Xs[ty + i * 8][kk];   // broadcast
#pragma unroll
            for (int j = 0; j < 8; ++j) bv[j] = Ws[kk][tx + j * 32];  // lane-consecutive
#pragma unroll
            for (int i = 0; i < 8; ++i)
#pragma unroll
                for (int j = 0; j < 8; ++j)
                    acc[i * 8 + j] += av[i] * bv[j];
        }
        __syncthreads();
    }
#pragma unroll
    for (int j = 0; j < 8; ++j) {
        int col = tx + j * 32;
        if (col < ND) {
            float bc = biasc[col];
#pragma unroll
            for (int i = 0; i < 8; ++i) {
                size_t row = m0 + ty + i * 8;
                out[row * ND + col] = acc[i * 8 + j] + bc;
            }
        }
    }
}

// ============================================================================
extern "C" void kernel_launch(void* const* d_in, const int* in_sizes, int n_in,
                              void* d_out, int out_size, void* d_ws, size_t ws_size,
                              hipStream_t stream) {
    const float* x       = (const float*)d_in[0];
    const float* Wg      = (const float*)d_in[1];
    const float* att_src = (const float*)d_in[2];
    const float* att_dst = (const float*)d_in[3];
    const float* bias_g  = (const float*)d_in[4];
    const float* Wp      = (const float*)d_in[5];
    const float* b_proj  = (const float*)d_in[6];
    float* out = (float*)d_out;
    float* ws  = (float*)d_ws;

    float* partial = ws;                          // 256*4096      = 1,048,576
    float* adj     = partial + 256 * 4096;        // 3969
    float* thresh  = adj + NC * NC;               // 63
    float* maskf   = thresh + NC;                 // 3969
    float* h0      = maskf + NC * NC;             // 63,000
    float* as_     = h0 + NC * NHD;               // 252
    float* ad_     = as_ + NC * NH;               // 252
    float* wsm     = ad_ + NC * NH;               // 15,876
    float* Wc      = wsm + NC * NC * NH;          // 62,500
    float* biasc   = Wc + NF * ND;                // 250  (total ~4.6 MB)

    k_wc<<<126, 256, 0, stream>>>(Wg, bias_g, Wp, b_proj, Wc, biasc);
    k_main<<<1008, 256, 0, stream>>>(x, Wc, biasc, out);
    k_adj_partial<<<256, 512, 0, stream>>>(x, partial);
    k_adj_reduce<<<16, 256, 0, stream>>>(partial, adj);
    k_thresh_mask<<<1, 256, 0, stream>>>(adj, thresh, maskf);
    k_h0<<<63, 256, 0, stream>>>(x, Wg, h0);
    k_asad<<<1, 256, 0, stream>>>(h0, att_src, att_dst, as_, ad_);
    k_soft<<<1, 256, 0, stream>>>(maskf, as_, ad_, wsm);
    k_out0<<<63, 256, 0, stream>>>(wsm, h0, bias_g, Wp, b_proj, out);
}

// Round 2
// 366.224 us; speedup vs baseline: 1.3783x; 1.3783x over previous
//
#include <hip/hip_runtime.h>
#include <math.h>

#define NB 1024
#define NC 63
#define NF 250
#define NH 4
#define ND 250
#define NHD 1000

typedef __bf16 bf16x8 __attribute__((ext_vector_type(8)));
typedef float f32x4 __attribute__((ext_vector_type(4)));

// ============================================================================
// Kernel A: per-batch normalize + 63x63 gram partials (unchanged from R1).
// ============================================================================
__global__ __launch_bounds__(512) void k_adj_partial(const float* __restrict__ x,
                                                     float* __restrict__ partial) {
    __shared__ __align__(16) float smem[16384];  // xsT[250][64] (16000) / red[8][64][32]
    __shared__ float psum[8][64], pss[8][64];
    __shared__ float meanv[64], sclv[64];
    const int t = threadIdx.x;
    const int lane = t & 63;
    const int g = t >> 6;
    const int f0 = g * 32;
    const int f1 = (f0 + 32 < NF) ? f0 + 32 : NF;
    const int tr = (lane >> 3) * 8;
    const int tc = (lane & 7) * 8;

    float acc[64];
#pragma unroll
    for (int a = 0; a < 64; ++a) acc[a] = 0.f;

    for (int bb = 0; bb < 4; ++bb) {
        const int b = blockIdx.x * 4 + bb;
        const float* xb = x + (size_t)b * (NC * NF);
        float s = 0.f, ss = 0.f;
        if (lane < NC) {
            for (int f = f0; f < f1; ++f) {
                float v = xb[lane * NF + f];
                s += v; ss += v * v;
                smem[f * 64 + lane] = v;
            }
        } else {
            for (int f = f0; f < f1; ++f) smem[f * 64 + 63] = 0.f;
        }
        psum[g][lane] = s; pss[g][lane] = ss;
        __syncthreads();
        if (t < 64) {
            float S = 0.f, SS = 0.f;
#pragma unroll
            for (int gg = 0; gg < 8; ++gg) { S += psum[gg][t]; SS += pss[gg][t]; }
            float m = S / (float)NF;
            float var = (SS - S * S / (float)NF) / (float)(NF - 1);
            float sc = 1.f / (sqrtf(var) + 1e-8f);
            if (t >= NC) { m = 0.f; sc = 0.f; }
            meanv[t] = m; sclv[t] = sc;
        }
        __syncthreads();
        if (lane < NC) {
            const float m = meanv[lane], sc = sclv[lane];
            for (int f = f0; f < f1; ++f)
                smem[f * 64 + lane] = (smem[f * 64 + lane] - m) * sc;
        }
        __syncthreads();
        for (int f = f0; f < f1; ++f) {
            const float4 a0 = *(const float4*)&smem[f * 64 + tr];
            const float4 a1 = *(const float4*)&smem[f * 64 + tr + 4];
            const float4 b0 = *(const float4*)&smem[f * 64 + tc];
            const float4 b1 = *(const float4*)&smem[f * 64 + tc + 4];
            const float av[8] = {a0.x,a0.y,a0.z,a0.w,a1.x,a1.y,a1.z,a1.w};
            const float bv[8] = {b0.x,b0.y,b0.z,b0.w,b1.x,b1.y,b1.z,b1.w};
#pragma unroll
            for (int i = 0; i < 8; ++i)
#pragma unroll
                for (int j = 0; j < 8; ++j)
                    acc[i * 8 + j] += av[i] * bv[j];
        }
        __syncthreads();
    }
    float* red = smem;
#pragma unroll
    for (int half = 0; half < 2; ++half) {
        __syncthreads();
#pragma unroll
        for (int j = 0; j < 32; ++j)
            red[g * 2048 + lane * 32 + ((j + lane) & 31)] = acc[half * 32 + j];
        __syncthreads();
        for (int k = 0; k < 4; ++k) {
            int e = t + k * 512;
            int tl = e >> 5, jp = e & 31;
            float sum = 0.f;
#pragma unroll
            for (int gg = 0; gg < 8; ++gg)
                sum += red[gg * 2048 + tl * 32 + ((jp + tl) & 31)];
            int a = half * 32 + jp;
            int row = (tl >> 3) * 8 + (a >> 3);
            int col = (tl & 7) * 8 + (a & 7);
            if (row < NC && col < NC)
                partial[(size_t)blockIdx.x * 4096 + row * 64 + col] = sum;
        }
    }
}

// ============================================================================
// Reduce 256 partials -> adj (63x63). grid 63 (one row per block).
// Lanes coalesced over columns; 4-way partial split over p + LDS combine.
// ============================================================================
__global__ __launch_bounds__(256) void k_adj_reduce(const float* __restrict__ partial,
                                                    float* __restrict__ adj) {
    __shared__ float red[4][64];
    const int row = blockIdx.x, t = threadIdx.x;
    const int c = t & 63, pg = t >> 6;
    float s = 0.f;
    const float* p = partial + (size_t)(pg * 64) * 4096 + row * 64 + c;
    for (int i = 0; i < 64; ++i) s += p[(size_t)i * 4096];
    red[pg][c] = s;
    __syncthreads();
    if (t < NC) {
        float tot = red[0][t] + red[1][t] + red[2][t] + red[3][t];
        adj[row * NC + t] = tot * (1.f / ((float)NF * (float)NB));
    }
}

// ============================================================================
// Per-row 8th-largest threshold + mask_full (unchanged)
// ============================================================================
__global__ void k_thresh_mask(const float* __restrict__ adj, float* __restrict__ thresh,
                              float* __restrict__ maskf) {
    int t = threadIdx.x;
    if (t < NC) {
        float prev = INFINITY;
        int krem = 8;
        float th = -INFINITY;
        for (int iter = 0; iter < 8; ++iter) {
            float vmax = -INFINITY; int cnt = 0;
            for (int j = 0; j < NC; ++j) {
                float v = adj[t * NC + j];
                if (v < prev) {
                    if (v > vmax) { vmax = v; cnt = 1; }
                    else if (v == vmax) cnt++;
                }
            }
            if (cnt >= krem) { th = vmax; break; }
            krem -= cnt; prev = vmax;
        }
        thresh[t] = th;
    }
    __syncthreads();
    for (int e = t; e < NC * NC; e += 256) {
        int i = e / NC, j = e % NC;
        float v = adj[e];
        bool m = (i == j) || ((v >= thresh[i]) && (v != 0.f));
        maskf[e] = m ? 1.f : 0.f;
    }
}

// ============================================================================
// h0 = x[0] @ W_gat   (63 x 1000)  fp32 exact (feeds attention path)
// ============================================================================
__global__ __launch_bounds__(256) void k_h0(const float* __restrict__ x,
                                            const float* __restrict__ Wg,
                                            float* __restrict__ h0) {
    __shared__ float xrow[NF];
    int c = blockIdx.x, t = threadIdx.x;
    if (t < NF) xrow[t] = x[c * NF + t];
    __syncthreads();
    int n0 = t, n1 = t + 256, n2 = t + 512;
    int n3 = (t + 768 < NHD) ? t + 768 : NHD - 1;
    float acc0 = 0, acc1 = 0, acc2 = 0, acc3 = 0;
    for (int f = 0; f < NF; ++f) {
        float xv = xrow[f];
        const float* wr = Wg + (size_t)f * NHD;
        acc0 += xv * wr[n0];
        acc1 += xv * wr[n1];
        acc2 += xv * wr[n2];
        acc3 += xv * wr[n3];
    }
    h0[c * NHD + n0] = acc0;
    h0[c * NHD + n1] = acc1;
    h0[c * NHD + n2] = acc2;
    if (t + 768 < NHD) h0[c * NHD + n3] = acc3;
}

// ============================================================================
// a_s[c,h], a_d[c,h] (unchanged)
// ============================================================================
__global__ void k_asad(const float* __restrict__ h0, const float* __restrict__ att_src,
                       const float* __restrict__ att_dst, float* __restrict__ as_,
                       float* __restrict__ ad_) {
    int t = threadIdx.x;
    if (t >= NC * NH) return;
    int c = t >> 2, h = t & 3;
    const float* hr = h0 + c * NHD + h * ND;
    const float* sp = att_src + h * ND;
    const float* dp = att_dst + h * ND;
    float s0 = 0.f, s1 = 0.f;
    for (int dd = 0; dd < ND; ++dd) { s0 += hr[dd] * sp[dd]; s1 += hr[dd] * dp[dd]; }
    as_[t] = s0; ad_[t] = s1;
}

// ============================================================================
// softmax over i of masked leaky_relu (unchanged)
// ============================================================================
__global__ void k_soft(const float* __restrict__ maskf, const float* __restrict__ as_,
                       const float* __restrict__ ad_, float* __restrict__ w) {
    int t = threadIdx.x;
    if (t >= NC * NH) return;
    int j = t >> 2, h = t & 3;
    float adv = ad_[j * 4 + h];
    float m = -INFINITY;
    for (int i = 0; i < NC; ++i) {
        if (maskf[i * NC + j] != 0.f) {
            float e = as_[i * 4 + h] + adv;
            e = e > 0.f ? e : 0.2f * e;
            m = fmaxf(m, e);
        }
    }
    float ssum = 0.f;
    for (int i = 0; i < NC; ++i) {
        float wv = 0.f;
        if (maskf[i * NC + j] != 0.f) {
            float e = as_[i * 4 + h] + adv;
            e = e > 0.f ? e : 0.2f * e;
            wv = expf(e - m);
            ssum += wv;
        }
        w[(i * NC + j) * 4 + h] = wv;
    }
    float inv = 1.f / ssum;
    for (int i = 0; i < NC; ++i)
        w[(i * NC + j) * 4 + h] *= inv;
}

// ============================================================================
// b=0 rows: att0 + projection. 512 threads, K split 2-way in proj phase.
// ============================================================================
__global__ __launch_bounds__(512) void k_out0(const float* __restrict__ w,
                                              const float* __restrict__ h0,
                                              const float* __restrict__ bias_gat,
                                              const float* __restrict__ Wp,
                                              const float* __restrict__ b_proj,
                                              float* __restrict__ out) {
    __shared__ float wcol[NC * NH];
    __shared__ float y[NHD];
    __shared__ float psum[2][256];
    int j = blockIdx.x, t = threadIdx.x;
    if (t < NC * NH) {
        int i = t >> 2, h = t & 3;
        wcol[t] = w[(i * NC + j) * 4 + h];
    }
    __syncthreads();
    for (int n = t; n < NHD; n += 512) {
        int h = n / ND;
        float acc = 0.f;
        for (int i = 0; i < NC; ++i)
            acc += wcol[i * 4 + h] * h0[i * NHD + n];
        y[n] = acc + bias_gat[n];
    }
    __syncthreads();
    int q = t >> 8, col = t & 255;
    float acc = 0.f;
    if (col < ND) {
        for (int k = q * 500; k < q * 500 + 500; ++k)
            acc += y[k] * Wp[(size_t)k * ND + col];
    }
    psum[q][col] = acc;
    __syncthreads();
    if (t < ND) out[j * ND + t] = psum[0][t] + psum[1][t] + b_proj[t];
}

// ============================================================================
// Stage A of Wc: split-K x4 partials of W_gat@W_proj; block 500 does biasc.
// grid 501 x 256.
// ============================================================================
__global__ __launch_bounds__(256) void k_wc_part(const float* __restrict__ Wg,
                                                 const float* __restrict__ bias_gat,
                                                 const float* __restrict__ Wp,
                                                 const float* __restrict__ b_proj,
                                                 float* __restrict__ pWc,
                                                 float* __restrict__ biasc) {
    __shared__ float rows[NHD];
    int b = blockIdx.x, t = threadIdx.x;
    if (b < 500) {
        int fb = (b >> 2) * 2, kq = b & 3;
        for (int idx = t; idx < 500; idx += 256) {
            int r = idx / 250, i = idx % 250;
            rows[idx] = Wg[(size_t)(fb + r) * NHD + kq * 250 + i];
        }
        __syncthreads();
        if (t < ND) {
            float a0 = 0.f, a1 = 0.f;
            const float* wp = Wp + (size_t)(kq * 250) * ND + t;
            for (int k = 0; k < 250; ++k) {
                float wv = wp[(size_t)k * ND];
                a0 += rows[k] * wv;
                a1 += rows[250 + k] * wv;
            }
            pWc[((size_t)kq * NF + fb) * ND + t] = a0;
            pWc[((size_t)kq * NF + fb + 1) * ND + t] = a1;
        }
    } else {
        for (int idx = t; idx < NHD; idx += 256) rows[idx] = bias_gat[idx];
        __syncthreads();
        if (t < ND) {
            float a0 = 0.f;
            for (int k = 0; k < NHD; ++k) a0 += rows[k] * Wp[(size_t)k * ND + t];
            biasc[t] = a0 + b_proj[t];
        }
    }
}

// ============================================================================
// Stage B: WcT[n][f] = bf16(sum_kq pWc[kq][f][n]), zero-padded to [256][256].
// grid 256 (n) x 256 (f): coalesced bf16 row writes.
// ============================================================================
__global__ __launch_bounds__(256) void k_wct(const float* __restrict__ pWc,
                                             __bf16* __restrict__ WcT) {
    int n = blockIdx.x, f = threadIdx.x;
    float v = 0.f;
    if (n < ND && f < NF) {
        size_t e = (size_t)f * ND + n;
        v = pWc[e] + pWc[(size_t)NF * ND + e] + pWc[(size_t)2 * NF * ND + e]
          + pWc[(size_t)3 * NF * ND + e];
    }
    WcT[n * 256 + f] = (__bf16)v;
}

// ============================================================================
// MAIN: out = x @ Wc + biasc via bf16 MFMA, zero LDS.
// Block 256 thr = 4 waves (1x4 along N); wave tile 64(M) x 64(N); grid 1008.
// A frags: direct float2 global loads + cvt (rows L1/L2-reused across waves).
// B frags: direct bf16x8 global loads from L2-resident WcT[256][256].
// Layouts: A row=lane&15, k=(lane>>4)*8+j; B col=lane&15 k-contig;
//          D col=lane&15, row=(lane>>4)*4+reg (m89-verified).
// ============================================================================
__global__ __launch_bounds__(256) void k_main_mfma(const float* __restrict__ x,
                                                   const __bf16* __restrict__ WcT,
                                                   const float* __restrict__ biasc,
                                                   float* __restrict__ out) {
    const int t = threadIdx.x;
    const int w = t >> 6;
    const int l = t & 63;
    const int l16 = l & 15, lq = l >> 4;
    const size_t m0 = (size_t)blockIdx.x * 64;
    const int nb = w * 64;

    f32x4 acc[4][4];
    const f32x4 z4 = {0.f, 0.f, 0.f, 0.f};
#pragma unroll
    for (int mi = 0; mi < 4; ++mi)
#pragma unroll
        for (int ni = 0; ni < 4; ++ni) acc[mi][ni] = z4;

    const float2 z2 = make_float2(0.f, 0.f);
    for (int kc = 0; kc < 8; ++kc) {
        const int kb = kc * 32 + lq * 8;   // this lane's k base (<= 248)
        bf16x8 bfr[4];
#pragma unroll
        for (int ni = 0; ni < 4; ++ni) {
            const int n = nb + ni * 16 + l16;
            bfr[ni] = *(const bf16x8*)(WcT + (size_t)n * 256 + kb);
        }
        bf16x8 afr[4];
#pragma unroll
        for (int mi = 0; mi < 4; ++mi) {
            const size_t row = m0 + mi * 16 + l16;
            const float* xr = x + row * NF + kb;
            const float2 p0 = *(const float2*)(xr);                      // kb<=248 always valid
            const float2 p1 = (kb + 2 < NF) ? *(const float2*)(xr + 2) : z2;
            const float2 p2 = (kb + 4 < NF) ? *(const float2*)(xr + 4) : z2;
            const float2 p3 = (kb + 6 < NF) ? *(const float2*)(xr + 6) : z2;
            bf16x8 a;
            a[0] = (__bf16)p0.x; a[1] = (__bf16)p0.y;
            a[2] = (__bf16)p1.x; a[3] = (__bf16)p1.y;
            a[4] = (__bf16)p2.x; a[5] = (__bf16)p2.y;
            a[6] = (__bf16)p3.x; a[7] = (__bf16)p3.y;
            afr[mi] = a;
        }
#pragma unroll
        for (int mi = 0; mi < 4; ++mi)
#pragma unroll
            for (int ni = 0; ni < 4; ++ni)
                acc[mi][ni] = __builtin_amdgcn_mfma_f32_16x16x32_bf16(
                    afr[mi], bfr[ni], acc[mi][ni], 0, 0, 0);
    }

#pragma unroll
    for (int ni = 0; ni < 4; ++ni) {
        const int col = nb + ni * 16 + l16;
        if (col < ND) {
            const float bc = biasc[col];
#pragma unroll
            for (int mi = 0; mi < 4; ++mi) {
                const size_t row = m0 + mi * 16 + lq * 4;
#pragma unroll
                for (int r = 0; r < 4; ++r)
                    out[(row + r) * ND + col] = acc[mi][ni][r] + bc;
            }
        }
    }
}

// ============================================================================
extern "C" void kernel_launch(void* const* d_in, const int* in_sizes, int n_in,
                              void* d_out, int out_size, void* d_ws, size_t ws_size,
                              hipStream_t stream) {
    const float* x       = (const float*)d_in[0];
    const float* Wg      = (const float*)d_in[1];
    const float* att_src = (const float*)d_in[2];
    const float* att_dst = (const float*)d_in[3];
    const float* bias_g  = (const float*)d_in[4];
    const float* Wp      = (const float*)d_in[5];
    const float* b_proj  = (const float*)d_in[6];
    float* out = (float*)d_out;
    float* ws  = (float*)d_ws;

    __bf16* WcT    = (__bf16*)ws;                 // 256*256 bf16 = 32768 floats
    float* partial = ws + 32768;                  // 256*4096 = 1,048,576
    float* adj     = partial + 256 * 4096;        // 3969
    float* thresh  = adj + NC * NC;               // 63
    float* maskf   = thresh + NC;                 // 3969
    float* h0      = maskf + NC * NC;             // 63,000
    float* as_     = h0 + NC * NHD;               // 252
    float* ad_     = as_ + NC * NH;               // 252
    float* wsm     = ad_ + NC * NH;               // 15,876
    float* pWc     = wsm + NC * NC * NH;          // 4*62,500 = 250,000
    float* biasc   = pWc + 4 * NF * ND;           // 250   (total ~5.7 MB)

    k_wc_part<<<501, 256, 0, stream>>>(Wg, bias_g, Wp, b_proj, pWc, biasc);
    k_wct<<<256, 256, 0, stream>>>(pWc, WcT);
    k_main_mfma<<<1008, 256, 0, stream>>>(x, WcT, biasc, out);
    k_adj_partial<<<256, 512, 0, stream>>>(x, partial);
    k_adj_reduce<<<63, 256, 0, stream>>>(partial, adj);
    k_thresh_mask<<<1, 256, 0, stream>>>(adj, thresh, maskf);
    k_h0<<<63, 256, 0, stream>>>(x, Wg, h0);
    k_asad<<<1, 256, 0, stream>>>(h0, att_src, att_dst, as_, ad_);
    k_soft<<<1, 256, 0, stream>>>(maskf, as_, ad_, wsm);
    k_out0<<<63, 512, 0, stream>>>(wsm, h0, bias_g, Wp, b_proj, out);
}

// Round 3
// 315.111 us; speedup vs baseline: 1.6018x; 1.1622x over previous
//
#include <hip/hip_runtime.h>
#include <math.h>

#define NB 1024
#define NC 63
#define NF 250
#define NH 4
#define ND 250
#define NHD 1000

typedef __bf16 bf16x8 __attribute__((ext_vector_type(8)));
typedef float f32x4 __attribute__((ext_vector_type(4)));

// ============================================================================
// k_adj_partial v3: raw gram + moment fixup (no normalize phases).
// grid 512 blocks x 512 thr; each block does 2 batches serially.
// Per batch: strided load (lane=channel) + moments -> barrier -> raw-gram
// 8x8 register tiles over per-wave f-slices -> LDS reduce of the 8 wave
// copies with fixup (G - F*m_i*m_j)*s_i*s_j fused into the readout.
// partial[blk][64][64] accumulates the block's 2 batches post-fixup.
// ============================================================================
__global__ __launch_bounds__(512) void k_adj_partial(const float* __restrict__ x,
                                                     float* __restrict__ partial) {
    __shared__ __align__(16) float smem[16384];  // xsT[250][64] / red[8][2048]
    __shared__ float psum[8][64], pss[8][64];
    __shared__ float meanv[64], sclv[64];
    const int t = threadIdx.x;
    const int lane = t & 63;   // channel c (load) / tile id (dot)
    const int g = t >> 6;      // wave id = f-group, 0..7
    const int f0 = g * 32;
    const int f1 = (f0 + 32 < NF) ? f0 + 32 : NF;   // g=7 -> 26 wide
    const int tr = (lane >> 3) * 8;
    const int tc = (lane & 7) * 8;

    float accF[8];
#pragma unroll
    for (int a = 0; a < 8; ++a) accF[a] = 0.f;

    for (int bb = 0; bb < 2; ++bb) {
        const int b = blockIdx.x * 2 + bb;
        const float* xb = x + (size_t)b * (NC * NF);
        __syncthreads();   // protect smem (prev readout) before overwrite
        // ---- load phase: raw transposed store + per-(c, f-group) moments
        float s = 0.f, ss = 0.f;
        if (lane < NC) {
            const float* xr = xb + lane * NF;
            for (int f = f0; f < f1; f += 2) {
                const float2 v = *(const float2*)(xr + f);
                s += v.x + v.y; ss += v.x * v.x + v.y * v.y;
                smem[f * 64 + lane] = v.x;
                smem[(f + 1) * 64 + lane] = v.y;
            }
        } else {
            for (int f = f0; f < f1; ++f) smem[f * 64 + lane] = 0.f;
        }
        psum[g][lane] = s; pss[g][lane] = ss;
        __syncthreads();
        // ---- moments: mean, 1/(std_ddof1+1e-8)
        if (t < 64) {
            float S = 0.f, SS = 0.f;
#pragma unroll
            for (int gg = 0; gg < 8; ++gg) { S += psum[gg][t]; SS += pss[gg][t]; }
            float m = S / (float)NF;
            float var = (SS - S * S / (float)NF) / (float)(NF - 1);
            float sc = 1.f / (sqrtf(var) + 1e-8f);
            if (t >= NC) { m = 0.f; sc = 0.f; }
            meanv[t] = m; sclv[t] = sc;
        }
        __syncthreads();
        // ---- raw gram over this wave's f-slice, 8x8 register tiles
        float acc[64];
#pragma unroll
        for (int a = 0; a < 64; ++a) acc[a] = 0.f;
#pragma unroll 2
        for (int f = f0; f < f1; ++f) {
            const float4 a0 = *(const float4*)&smem[f * 64 + tr];
            const float4 a1 = *(const float4*)&smem[f * 64 + tr + 4];
            const float4 b0 = *(const float4*)&smem[f * 64 + tc];
            const float4 b1 = *(const float4*)&smem[f * 64 + tc + 4];
            const float av[8] = {a0.x,a0.y,a0.z,a0.w,a1.x,a1.y,a1.z,a1.w};
            const float bv[8] = {b0.x,b0.y,b0.z,b0.w,b1.x,b1.y,b1.z,b1.w};
#pragma unroll
            for (int i = 0; i < 8; ++i)
#pragma unroll
                for (int j = 0; j < 8; ++j)
                    acc[i * 8 + j] += av[i] * bv[j];
        }
        // ---- reduce 8 wave copies + fixup at readout (rotation-swizzled)
        float* red = smem;
#pragma unroll
        for (int half = 0; half < 2; ++half) {
            __syncthreads();
#pragma unroll
            for (int j = 0; j < 32; ++j)
                red[g * 2048 + lane * 32 + ((j + lane) & 31)] = acc[half * 32 + j];
            __syncthreads();
#pragma unroll
            for (int k = 0; k < 4; ++k) {
                int e = t + k * 512;
                int tl = e >> 5, jp = e & 31;
                float sum = 0.f;
#pragma unroll
                for (int gg = 0; gg < 8; ++gg)
                    sum += red[gg * 2048 + tl * 32 + ((jp + tl) & 31)];
                int a = half * 32 + jp;
                int row = (tl >> 3) * 8 + (a >> 3);
                int col = (tl & 7) * 8 + (a & 7);
                float fixed = (sum - (float)NF * meanv[row] * meanv[col])
                              * sclv[row] * sclv[col];
                accF[half * 4 + k] += fixed;
            }
        }
    }
    // ---- write block partial
#pragma unroll
    for (int half = 0; half < 2; ++half)
#pragma unroll
        for (int k = 0; k < 4; ++k) {
            int e = t + k * 512;
            int tl = e >> 5, jp = e & 31;
            int a = half * 32 + jp;
            int row = (tl >> 3) * 8 + (a >> 3);
            int col = (tl & 7) * 8 + (a & 7);
            partial[(size_t)blockIdx.x * 4096 + row * 64 + col] = accF[half * 4 + k];
        }
}

// ============================================================================
// Reduce 512 partials -> adj (63x63). grid 63 rows x 512 thr (8 groups x 64c).
// ============================================================================
__global__ __launch_bounds__(512) void k_adj_reduce(const float* __restrict__ partial,
                                                    float* __restrict__ adj) {
    __shared__ float red[8][64];
    const int row = blockIdx.x, t = threadIdx.x;
    const int c = t & 63, g = t >> 6;
    float s = 0.f;
    const float* p = partial + (size_t)(g * 64) * 4096 + row * 64 + c;
#pragma unroll 8
    for (int i = 0; i < 64; ++i) s += p[(size_t)i * 4096];
    red[g][c] = s;
    __syncthreads();
    if (t < NC) {
        float tot = 0.f;
#pragma unroll
        for (int gg = 0; gg < 8; ++gg) tot += red[gg][t];
        adj[row * NC + t] = tot * (1.f / ((float)NF * (float)NB));
    }
}

// ============================================================================
// h0 = x[0] @ W_gat  (63 x 1000) + fused a_s/a_d per-head dots. grid 63.
// ============================================================================
__global__ __launch_bounds__(256) void k_h0asad(const float* __restrict__ x,
                                                const float* __restrict__ Wg,
                                                const float* __restrict__ att_src,
                                                const float* __restrict__ att_dst,
                                                float* __restrict__ h0,
                                                float* __restrict__ as_,
                                                float* __restrict__ ad_) {
    __shared__ float xrow[NF];
    __shared__ float y[NHD];
    __shared__ float red[256], red2[256];
    const int c = blockIdx.x, t = threadIdx.x;
    if (t < NF) xrow[t] = x[c * NF + t];
    __syncthreads();
    int n0 = t, n1 = t + 256, n2 = t + 512;
    int n3 = (t + 768 < NHD) ? t + 768 : NHD - 1;
    float acc0 = 0, acc1 = 0, acc2 = 0, acc3 = 0;
    for (int f = 0; f < NF; ++f) {
        float xv = xrow[f];
        const float* wr = Wg + (size_t)f * NHD;
        acc0 += xv * wr[n0];
        acc1 += xv * wr[n1];
        acc2 += xv * wr[n2];
        acc3 += xv * wr[n3];
    }
    h0[c * NHD + n0] = acc0; y[n0] = acc0;
    h0[c * NHD + n1] = acc1; y[n1] = acc1;
    h0[c * NHD + n2] = acc2; y[n2] = acc2;
    if (t + 768 < NHD) { h0[c * NHD + n3] = acc3; y[n3] = acc3; }
    __syncthreads();
    for (int h = 0; h < NH; ++h) {
        float vs = 0.f, vd = 0.f;
        if (t < ND) {
            float yv = y[h * ND + t];
            vs = yv * att_src[h * ND + t];
            vd = yv * att_dst[h * ND + t];
        }
        red[t] = vs; red2[t] = vd;
        __syncthreads();
        if (t < 128) { red[t] += red[t + 128]; red2[t] += red2[t + 128]; }
        __syncthreads();
        if (t < 64) { red[t] += red[t + 64]; red2[t] += red2[t + 64]; }
        __syncthreads();
        if (t < 64) {
            float r = red[t], r2 = red2[t];
#pragma unroll
            for (int off = 32; off >= 1; off >>= 1) {
                r += __shfl_down(r, off);
                r2 += __shfl_down(r2, off);
            }
            if (t == 0) { as_[c * NH + h] = r; ad_[c * NH + h] = r2; }
        }
        __syncthreads();
    }
}

// ============================================================================
// Fused: per-row top-8 threshold + masked leaky-relu softmax over axis 0.
// grid 1 x 256. mask computed inline from adj (no maskf buffer).
// ============================================================================
__global__ void k_mask_soft(const float* __restrict__ adj, const float* __restrict__ as_,
                            const float* __restrict__ ad_, float* __restrict__ w) {
    __shared__ float th[NC];
    const int t = threadIdx.x;
    if (t < NC) {
        float prev = INFINITY;
        int krem = 8;                       // TOP_K
        float v_th = -INFINITY;
        for (int iter = 0; iter < 8; ++iter) {
            float vmax = -INFINITY; int cnt = 0;
            for (int j = 0; j < NC; ++j) {
                float v = adj[t * NC + j];
                if (v < prev) {
                    if (v > vmax) { vmax = v; cnt = 1; }
                    else if (v == vmax) cnt++;
                }
            }
            if (cnt >= krem) { v_th = vmax; break; }
            krem -= cnt; prev = vmax;
        }
        th[t] = v_th;
    }
    __syncthreads();
    if (t >= NC * NH) return;
    const int j = t >> 2, h = t & 3;
    const float adv = ad_[j * NH + h];
    float m = -INFINITY;
    for (int i = 0; i < NC; ++i) {
        float a = adj[i * NC + j];
        bool msk = (i == j) || ((a >= th[i]) && (a != 0.f));
        if (msk) {
            float e = as_[i * NH + h] + adv;
            e = e > 0.f ? e : 0.2f * e;
            m = fmaxf(m, e);
        }
    }
    float ssum = 0.f;
    for (int i = 0; i < NC; ++i) {
        float a = adj[i * NC + j];
        bool msk = (i == j) || ((a >= th[i]) && (a != 0.f));
        float wv = 0.f;
        if (msk) {
            float e = as_[i * NH + h] + adv;
            e = e > 0.f ? e : 0.2f * e;
            wv = expf(e - m);
            ssum += wv;
        }
        w[(i * NC + j) * NH + h] = wv;
    }
    const float inv = 1.f / ssum;
    for (int i = 0; i < NC; ++i)
        w[(i * NC + j) * NH + h] *= inv;
}

// ============================================================================
// b=0 rows: att0 + projection. grid 63 x 512.
// ============================================================================
__global__ __launch_bounds__(512) void k_out0(const float* __restrict__ w,
                                              const float* __restrict__ h0,
                                              const float* __restrict__ bias_gat,
                                              const float* __restrict__ Wp,
                                              const float* __restrict__ b_proj,
                                              float* __restrict__ out) {
    __shared__ float wcol[NC * NH];
    __shared__ float y[NHD];
    __shared__ float psum[2][256];
    const int j = blockIdx.x, t = threadIdx.x;
    if (t < NC * NH) {
        int i = t >> 2, h = t & 3;
        wcol[t] = w[(i * NC + j) * NH + h];
    }
    __syncthreads();
    for (int n = t; n < NHD; n += 512) {
        int h = n / ND;
        float acc = 0.f;
        for (int i = 0; i < NC; ++i)
            acc += wcol[i * NH + h] * h0[i * NHD + n];
        y[n] = acc + bias_gat[n];
    }
    __syncthreads();
    const int q = t >> 8, col = t & 255;
    float acc = 0.f;
    if (col < ND) {
        for (int k = q * 500; k < q * 500 + 500; ++k)
            acc += y[k] * Wp[(size_t)k * ND + col];
    }
    psum[q][col] = acc;
    __syncthreads();
    if (t < ND) out[j * ND + t] = psum[0][t] + psum[1][t] + b_proj[t];
}

// ============================================================================
// Wc split-K x8 partials, stored TRANSPOSED pWcT[kq][n][256f] so the combine
// kernel is fully coalesced. blocks 0..999: (2 Wg rows) x (k-chunk of 125);
// blocks 1000..1007: biasc partials.
// ============================================================================
__global__ __launch_bounds__(256) void k_wc_part(const float* __restrict__ Wg,
                                                 const float* __restrict__ bias_gat,
                                                 const float* __restrict__ Wp,
                                                 float* __restrict__ pWcT,
                                                 float* __restrict__ pbias) {
    __shared__ float rows[250];
    const int b = blockIdx.x, t = threadIdx.x;
    if (b < 1000) {
        const int fb = (b >> 3) * 2, kq = b & 7;
        if (t < 250)
            rows[t] = Wg[(size_t)(fb + t / 125) * NHD + kq * 125 + (t % 125)];
        __syncthreads();
        if (t < ND) {
            float a0 = 0.f, a1 = 0.f;
            const float* wp = Wp + (size_t)(kq * 125) * ND + t;
            for (int k = 0; k < 125; ++k) {
                float wv = wp[(size_t)k * ND];
                a0 += rows[k] * wv;
                a1 += rows[125 + k] * wv;
            }
            pWcT[(size_t)kq * 65536 + (size_t)t * 256 + fb] = a0;
            pWcT[(size_t)kq * 65536 + (size_t)t * 256 + fb + 1] = a1;
        }
    } else {
        const int kq = b - 1000;
        if (t < ND) {
            float acc = 0.f;
            for (int k = kq * 125; k < kq * 125 + 125; ++k)
                acc += bias_gat[k] * Wp[(size_t)k * ND + t];
            pbias[kq * 256 + t] = acc;
        }
    }
}

// ============================================================================
// Combine: WcT[n][f] bf16 (padded [256][256]); block 256 does biasc.
// Fully coalesced reads and writes.
// ============================================================================
__global__ __launch_bounds__(256) void k_wct(const float* __restrict__ pWcT,
                                             const float* __restrict__ pbias,
                                             const float* __restrict__ b_proj,
                                             __bf16* __restrict__ WcT,
                                             float* __restrict__ biasc) {
    const int n = blockIdx.x, t = threadIdx.x;
    if (n < 256) {
        float v = 0.f;
        if (n < ND && t < NF) {
            size_t e = (size_t)n * 256 + t;
#pragma unroll
            for (int kq = 0; kq < 8; ++kq) v += pWcT[(size_t)kq * 65536 + e];
        }
        WcT[n * 256 + t] = (__bf16)v;
    } else {
        if (t < ND) {
            float v = 0.f;
#pragma unroll
            for (int kq = 0; kq < 8; ++kq) v += pbias[kq * 256 + t];
            biasc[t] = v + b_proj[t];
        }
    }
}

// ============================================================================
// MAIN: out = x @ Wc + biasc via bf16 MFMA, zero LDS (unchanged from R2).
// ============================================================================
__global__ __launch_bounds__(256) void k_main_mfma(const float* __restrict__ x,
                                                   const __bf16* __restrict__ WcT,
                                                   const float* __restrict__ biasc,
                                                   float* __restrict__ out) {
    const int t = threadIdx.x;
    const int w = t >> 6;
    const int l = t & 63;
    const int l16 = l & 15, lq = l >> 4;
    const size_t m0 = (size_t)blockIdx.x * 64;
    const int nb = w * 64;

    f32x4 acc[4][4];
    const f32x4 z4 = {0.f, 0.f, 0.f, 0.f};
#pragma unroll
    for (int mi = 0; mi < 4; ++mi)
#pragma unroll
        for (int ni = 0; ni < 4; ++ni) acc[mi][ni] = z4;

    const float2 z2 = make_float2(0.f, 0.f);
    for (int kc = 0; kc < 8; ++kc) {
        const int kb = kc * 32 + lq * 8;
        bf16x8 bfr[4];
#pragma unroll
        for (int ni = 0; ni < 4; ++ni) {
            const int n = nb + ni * 16 + l16;
            bfr[ni] = *(const bf16x8*)(WcT + (size_t)n * 256 + kb);
        }
        bf16x8 afr[4];
#pragma unroll
        for (int mi = 0; mi < 4; ++mi) {
            const size_t row = m0 + mi * 16 + l16;
            const float* xr = x + row * NF + kb;
            const float2 p0 = *(const float2*)(xr);
            const float2 p1 = (kb + 2 < NF) ? *(const float2*)(xr + 2) : z2;
            const float2 p2 = (kb + 4 < NF) ? *(const float2*)(xr + 4) : z2;
            const float2 p3 = (kb + 6 < NF) ? *(const float2*)(xr + 6) : z2;
            bf16x8 a;
            a[0] = (__bf16)p0.x; a[1] = (__bf16)p0.y;
            a[2] = (__bf16)p1.x; a[3] = (__bf16)p1.y;
            a[4] = (__bf16)p2.x; a[5] = (__bf16)p2.y;
            a[6] = (__bf16)p3.x; a[7] = (__bf16)p3.y;
            afr[mi] = a;
        }
#pragma unroll
        for (int mi = 0; mi < 4; ++mi)
#pragma unroll
            for (int ni = 0; ni < 4; ++ni)
                acc[mi][ni] = __builtin_amdgcn_mfma_f32_16x16x32_bf16(
                    afr[mi], bfr[ni], acc[mi][ni], 0, 0, 0);
    }

#pragma unroll
    for (int ni = 0; ni < 4; ++ni) {
        const int col = nb + ni * 16 + l16;
        if (col < ND) {
            const float bc = biasc[col];
#pragma unroll
            for (int mi = 0; mi < 4; ++mi) {
                const size_t row = m0 + mi * 16 + lq * 4;
#pragma unroll
                for (int r = 0; r < 4; ++r)
                    out[(row + r) * ND + col] = acc[mi][ni][r] + bc;
            }
        }
    }
}

// ============================================================================
extern "C" void kernel_launch(void* const* d_in, const int* in_sizes, int n_in,
                              void* d_out, int out_size, void* d_ws, size_t ws_size,
                              hipStream_t stream) {
    const float* x       = (const float*)d_in[0];
    const float* Wg      = (const float*)d_in[1];
    const float* att_src = (const float*)d_in[2];
    const float* att_dst = (const float*)d_in[3];
    const float* bias_g  = (const float*)d_in[4];
    const float* Wp      = (const float*)d_in[5];
    const float* b_proj  = (const float*)d_in[6];
    float* out = (float*)d_out;
    float* ws  = (float*)d_ws;

    __bf16* WcT    = (__bf16*)ws;                 // 65536 bf16 = 32768 floats
    float* pWcT    = ws + 32768;                  // 8*65536 = 524288
    float* pbias   = pWcT + 8 * 65536;            // 2048
    float* biasc   = pbias + 2048;                // 256
    float* partial = biasc + 256;                 // 512*4096 = 2,097,152
    float* adj     = partial + 512 * 4096;        // 3969
    float* h0      = adj + NC * NC;               // 63,000
    float* as_     = h0 + NC * NHD;               // 252
    float* ad_     = as_ + NC * NH;               // 252
    float* wsm     = ad_ + NC * NH;               // 15,876  (total ~10.9 MB)

    k_wc_part<<<1008, 256, 0, stream>>>(Wg, bias_g, Wp, pWcT, pbias);
    k_wct<<<257, 256, 0, stream>>>(pWcT, pbias, b_proj, WcT, biasc);
    k_main_mfma<<<1008, 256, 0, stream>>>(x, WcT, biasc, out);
    k_adj_partial<<<512, 512, 0, stream>>>(x, partial);
    k_adj_reduce<<<63, 512, 0, stream>>>(partial, adj);
    k_h0asad<<<63, 256, 0, stream>>>(x, Wg, att_src, att_dst, h0, as_, ad_);
    k_mask_soft<<<1, 256, 0, stream>>>(adj, as_, ad_, wsm);
    k_out0<<<63, 512, 0, stream>>>(wsm, h0, bias_g, Wp, b_proj, out);
}

// Round 4
// 274.219 us; speedup vs baseline: 1.8407x; 1.1491x over previous
//
#include <hip/hip_runtime.h>
#include <math.h>

#define NB 1024
#define NC 63
#define NF 250
#define NH 4
#define ND 250
#define NHD 1000

typedef __bf16 bf16x8 __attribute__((ext_vector_type(8)));
typedef float f32x4 __attribute__((ext_vector_type(4)));

// ============================================================================
// k_adj_partial v3: raw gram + moment fixup (no normalize phases).
// grid 512 blocks x 512 thr; each block does 2 batches serially.
// ============================================================================
__global__ __launch_bounds__(512) void k_adj_partial(const float* __restrict__ x,
                                                     float* __restrict__ partial) {
    __shared__ __align__(16) float smem[16384];  // xsT[250][64] / red[8][2048]
    __shared__ float psum[8][64], pss[8][64];
    __shared__ float meanv[64], sclv[64];
    const int t = threadIdx.x;
    const int lane = t & 63;   // channel c (load) / tile id (dot)
    const int g = t >> 6;      // wave id = f-group, 0..7
    const int f0 = g * 32;
    const int f1 = (f0 + 32 < NF) ? f0 + 32 : NF;   // g=7 -> 26 wide
    const int tr = (lane >> 3) * 8;
    const int tc = (lane & 7) * 8;

    float accF[8];
#pragma unroll
    for (int a = 0; a < 8; ++a) accF[a] = 0.f;

    for (int bb = 0; bb < 2; ++bb) {
        const int b = blockIdx.x * 2 + bb;
        const float* xb = x + (size_t)b * (NC * NF);
        __syncthreads();   // protect smem (prev readout) before overwrite
        float s = 0.f, ss = 0.f;
        if (lane < NC) {
            const float* xr = xb + lane * NF;
            for (int f = f0; f < f1; f += 2) {
                const float2 v = *(const float2*)(xr + f);
                s += v.x + v.y; ss += v.x * v.x + v.y * v.y;
                smem[f * 64 + lane] = v.x;
                smem[(f + 1) * 64 + lane] = v.y;
            }
        } else {
            for (int f = f0; f < f1; ++f) smem[f * 64 + lane] = 0.f;
        }
        psum[g][lane] = s; pss[g][lane] = ss;
        __syncthreads();
        if (t < 64) {
            float S = 0.f, SS = 0.f;
#pragma unroll
            for (int gg = 0; gg < 8; ++gg) { S += psum[gg][t]; SS += pss[gg][t]; }
            float m = S / (float)NF;
            float var = (SS - S * S / (float)NF) / (float)(NF - 1);
            float sc = 1.f / (sqrtf(var) + 1e-8f);
            if (t >= NC) { m = 0.f; sc = 0.f; }
            meanv[t] = m; sclv[t] = sc;
        }
        __syncthreads();
        float acc[64];
#pragma unroll
        for (int a = 0; a < 64; ++a) acc[a] = 0.f;
#pragma unroll 2
        for (int f = f0; f < f1; ++f) {
            const float4 a0 = *(const float4*)&smem[f * 64 + tr];
            const float4 a1 = *(const float4*)&smem[f * 64 + tr + 4];
            const float4 b0 = *(const float4*)&smem[f * 64 + tc];
            const float4 b1 = *(const float4*)&smem[f * 64 + tc + 4];
            const float av[8] = {a0.x,a0.y,a0.z,a0.w,a1.x,a1.y,a1.z,a1.w};
            const float bv[8] = {b0.x,b0.y,b0.z,b0.w,b1.x,b1.y,b1.z,b1.w};
#pragma unroll
            for (int i = 0; i < 8; ++i)
#pragma unroll
                for (int j = 0; j < 8; ++j)
                    acc[i * 8 + j] += av[i] * bv[j];
        }
        float* red = smem;
#pragma unroll
        for (int half = 0; half < 2; ++half) {
            __syncthreads();
#pragma unroll
            for (int j = 0; j < 32; ++j)
                red[g * 2048 + lane * 32 + ((j + lane) & 31)] = acc[half * 32 + j];
            __syncthreads();
#pragma unroll
            for (int k = 0; k < 4; ++k) {
                int e = t + k * 512;
                int tl = e >> 5, jp = e & 31;
                float sum = 0.f;
#pragma unroll
                for (int gg = 0; gg < 8; ++gg)
                    sum += red[gg * 2048 + tl * 32 + ((jp + tl) & 31)];
                int a = half * 32 + jp;
                int row = (tl >> 3) * 8 + (a >> 3);
                int col = (tl & 7) * 8 + (a & 7);
                float fixed = (sum - (float)NF * meanv[row] * meanv[col])
                              * sclv[row] * sclv[col];
                accF[half * 4 + k] += fixed;
            }
        }
    }
#pragma unroll
    for (int half = 0; half < 2; ++half)
#pragma unroll
        for (int k = 0; k < 4; ++k) {
            int e = t + k * 512;
            int tl = e >> 5, jp = e & 31;
            int a = half * 32 + jp;
            int row = (tl >> 3) * 8 + (a >> 3);
            int col = (tl & 7) * 8 + (a & 7);
            partial[(size_t)blockIdx.x * 4096 + row * 64 + col] = accF[half * 4 + k];
        }
}

// ============================================================================
// Reduce 512 partials -> adj (63x63). grid 63 rows x 512 thr.
// ============================================================================
__global__ __launch_bounds__(512) void k_adj_reduce(const float* __restrict__ partial,
                                                    float* __restrict__ adj) {
    __shared__ float red[8][64];
    const int row = blockIdx.x, t = threadIdx.x;
    const int c = t & 63, g = t >> 6;
    float s = 0.f;
    const float* p = partial + (size_t)(g * 64) * 4096 + row * 64 + c;
#pragma unroll 8
    for (int i = 0; i < 64; ++i) s += p[(size_t)i * 4096];
    red[g][c] = s;
    __syncthreads();
    if (t < NC) {
        float tot = 0.f;
#pragma unroll
        for (int gg = 0; gg < 8; ++gg) tot += red[gg][t];
        adj[row * NC + t] = tot * (1.f / ((float)NF * (float)NB));
    }
}

// ============================================================================
// h0 = x[0] @ W_gat  (63 x 1000) + fused a_s/a_d per-head dots. grid 63.
// ============================================================================
__global__ __launch_bounds__(256) void k_h0asad(const float* __restrict__ x,
                                                const float* __restrict__ Wg,
                                                const float* __restrict__ att_src,
                                                const float* __restrict__ att_dst,
                                                float* __restrict__ h0,
                                                float* __restrict__ as_,
                                                float* __restrict__ ad_) {
    __shared__ float xrow[NF];
    __shared__ float y[NHD];
    __shared__ float red[256], red2[256];
    const int c = blockIdx.x, t = threadIdx.x;
    if (t < NF) xrow[t] = x[c * NF + t];
    __syncthreads();
    int n0 = t, n1 = t + 256, n2 = t + 512;
    int n3 = (t + 768 < NHD) ? t + 768 : NHD - 1;
    float acc0 = 0, acc1 = 0, acc2 = 0, acc3 = 0;
    for (int f = 0; f < NF; ++f) {
        float xv = xrow[f];
        const float* wr = Wg + (size_t)f * NHD;
        acc0 += xv * wr[n0];
        acc1 += xv * wr[n1];
        acc2 += xv * wr[n2];
        acc3 += xv * wr[n3];
    }
    h0[c * NHD + n0] = acc0; y[n0] = acc0;
    h0[c * NHD + n1] = acc1; y[n1] = acc1;
    h0[c * NHD + n2] = acc2; y[n2] = acc2;
    if (t + 768 < NHD) { h0[c * NHD + n3] = acc3; y[n3] = acc3; }
    __syncthreads();
    for (int h = 0; h < NH; ++h) {
        float vs = 0.f, vd = 0.f;
        if (t < ND) {
            float yv = y[h * ND + t];
            vs = yv * att_src[h * ND + t];
            vd = yv * att_dst[h * ND + t];
        }
        red[t] = vs; red2[t] = vd;
        __syncthreads();
        if (t < 128) { red[t] += red[t + 128]; red2[t] += red2[t + 128]; }
        __syncthreads();
        if (t < 64) { red[t] += red[t + 64]; red2[t] += red2[t + 64]; }
        __syncthreads();
        if (t < 64) {
            float r = red[t], r2 = red2[t];
#pragma unroll
            for (int off = 32; off >= 1; off >>= 1) {
                r += __shfl_down(r, off);
                r2 += __shfl_down(r2, off);
            }
            if (t == 0) { as_[c * NH + h] = r; ad_[c * NH + h] = r2; }
        }
        __syncthreads();
    }
}

// ============================================================================
// Fused threshold + masked softmax, v2: EVERYTHING staged in LDS first
// (adj 15.9KB + w 63.5KB + as/ad 2KB < 160KB). The R3 version was a
// global-latency chain (120us, 0.045% occupancy); all inner loops now hit
// LDS only, and the w write-back is coalesced.
// ============================================================================
__global__ __launch_bounds__(256) void k_mask_soft(const float* __restrict__ adj,
                                                   const float* __restrict__ as_,
                                                   const float* __restrict__ ad_,
                                                   float* __restrict__ w) {
    __shared__ float adjS[NC * NC];
    __shared__ float wS[NC * NC * NH];
    __shared__ float asS[NC * NH], adS[NC * NH];
    __shared__ float th[NC];
    const int t = threadIdx.x;
    for (int e = t; e < NC * NC; e += 256) adjS[e] = adj[e];
    if (t < NC * NH) { asS[t] = as_[t]; adS[t] = ad_[t]; }
    __syncthreads();
    if (t < NC) {
        float prev = INFINITY;
        int krem = 8;                       // TOP_K
        float v_th = -INFINITY;
        for (int iter = 0; iter < 8; ++iter) {
            float vmax = -INFINITY; int cnt = 0;
            for (int j = 0; j < NC; ++j) {
                float v = adjS[t * NC + j];
                if (v < prev) {
                    if (v > vmax) { vmax = v; cnt = 1; }
                    else if (v == vmax) cnt++;
                }
            }
            if (cnt >= krem) { v_th = vmax; break; }
            krem -= cnt; prev = vmax;
        }
        th[t] = v_th;
    }
    __syncthreads();
    if (t < NC * NH) {
        const int j = t >> 2, h = t & 3;
        const float adv = adS[j * NH + h];
        float m = -INFINITY;
        for (int i = 0; i < NC; ++i) {
            float a = adjS[i * NC + j];
            bool msk = (i == j) || ((a >= th[i]) && (a != 0.f));
            if (msk) {
                float e = asS[i * NH + h] + adv;
                e = e > 0.f ? e : 0.2f * e;
                m = fmaxf(m, e);
            }
        }
        float ssum = 0.f;
        for (int i = 0; i < NC; ++i) {
            float a = adjS[i * NC + j];
            bool msk = (i == j) || ((a >= th[i]) && (a != 0.f));
            float wv = 0.f;
            if (msk) {
                float e = asS[i * NH + h] + adv;
                e = e > 0.f ? e : 0.2f * e;
                wv = __expf(e - m);
                ssum += wv;
            }
            wS[(i * NC + j) * NH + h] = wv;
        }
        const float inv = 1.f / ssum;
        for (int i = 0; i < NC; ++i)
            wS[(i * NC + j) * NH + h] *= inv;
    }
    __syncthreads();
    for (int e = t; e < NC * NC * NH; e += 256) w[e] = wS[e];
}

// ============================================================================
// b=0 rows: att0 + projection. grid 63 x 512.
// ============================================================================
__global__ __launch_bounds__(512) void k_out0(const float* __restrict__ w,
                                              const float* __restrict__ h0,
                                              const float* __restrict__ bias_gat,
                                              const float* __restrict__ Wp,
                                              const float* __restrict__ b_proj,
                                              float* __restrict__ out) {
    __shared__ float wcol[NC * NH];
    __shared__ float y[NHD];
    __shared__ float psum[2][256];
    const int j = blockIdx.x, t = threadIdx.x;
    if (t < NC * NH) {
        int i = t >> 2, h = t & 3;
        wcol[t] = w[(i * NC + j) * NH + h];
    }
    __syncthreads();
    for (int n = t; n < NHD; n += 512) {
        int h = n / ND;
        float acc = 0.f;
        for (int i = 0; i < NC; ++i)
            acc += wcol[i * NH + h] * h0[i * NHD + n];
        y[n] = acc + bias_gat[n];
    }
    __syncthreads();
    const int q = t >> 8, col = t & 255;
    float acc = 0.f;
    if (col < ND) {
        for (int k = q * 500; k < q * 500 + 500; ++k)
            acc += y[k] * Wp[(size_t)k * ND + col];
    }
    psum[q][col] = acc;
    __syncthreads();
    if (t < ND) out[j * ND + t] = psum[0][t] + psum[1][t] + b_proj[t];
}

// ============================================================================
// Wc split-K x8 partials, stored TRANSPOSED pWcT[kq][n][256f].
// ============================================================================
__global__ __launch_bounds__(256) void k_wc_part(const float* __restrict__ Wg,
                                                 const float* __restrict__ bias_gat,
                                                 const float* __restrict__ Wp,
                                                 float* __restrict__ pWcT,
                                                 float* __restrict__ pbias) {
    __shared__ float rows[250];
    const int b = blockIdx.x, t = threadIdx.x;
    if (b < 1000) {
        const int fb = (b >> 3) * 2, kq = b & 7;
        if (t < 250)
            rows[t] = Wg[(size_t)(fb + t / 125) * NHD + kq * 125 + (t % 125)];
        __syncthreads();
        if (t < ND) {
            float a0 = 0.f, a1 = 0.f;
            const float* wp = Wp + (size_t)(kq * 125) * ND + t;
            for (int k = 0; k < 125; ++k) {
                float wv = wp[(size_t)k * ND];
                a0 += rows[k] * wv;
                a1 += rows[125 + k] * wv;
            }
            pWcT[(size_t)kq * 65536 + (size_t)t * 256 + fb] = a0;
            pWcT[(size_t)kq * 65536 + (size_t)t * 256 + fb + 1] = a1;
        }
    } else {
        const int kq = b - 1000;
        if (t < ND) {
            float acc = 0.f;
            for (int k = kq * 125; k < kq * 125 + 125; ++k)
                acc += bias_gat[k] * Wp[(size_t)k * ND + t];
            pbias[kq * 256 + t] = acc;
        }
    }
}

// ============================================================================
// Combine: WcT[n][f] bf16 (padded [256][256]); block 256 does biasc.
// ============================================================================
__global__ __launch_bounds__(256) void k_wct(const float* __restrict__ pWcT,
                                             const float* __restrict__ pbias,
                                             const float* __restrict__ b_proj,
                                             __bf16* __restrict__ WcT,
                                             float* __restrict__ biasc) {
    const int n = blockIdx.x, t = threadIdx.x;
    if (n < 256) {
        float v = 0.f;
        if (n < ND && t < NF) {
            size_t e = (size_t)n * 256 + t;
#pragma unroll
            for (int kq = 0; kq < 8; ++kq) v += pWcT[(size_t)kq * 65536 + e];
        }
        WcT[n * 256 + t] = (__bf16)v;
    } else {
        if (t < ND) {
            float v = 0.f;
#pragma unroll
            for (int kq = 0; kq < 8; ++kq) v += pbias[kq * 256 + t];
            biasc[t] = v + b_proj[t];
        }
    }
}

// ============================================================================
// MAIN: out = x @ Wc + biasc via bf16 MFMA, zero LDS (unchanged).
// ============================================================================
__global__ __launch_bounds__(256) void k_main_mfma(const float* __restrict__ x,
                                                   const __bf16* __restrict__ WcT,
                                                   const float* __restrict__ biasc,
                                                   float* __restrict__ out) {
    const int t = threadIdx.x;
    const int w = t >> 6;
    const int l = t & 63;
    const int l16 = l & 15, lq = l >> 4;
    const size_t m0 = (size_t)blockIdx.x * 64;
    const int nb = w * 64;

    f32x4 acc[4][4];
    const f32x4 z4 = {0.f, 0.f, 0.f, 0.f};
#pragma unroll
    for (int mi = 0; mi < 4; ++mi)
#pragma unroll
        for (int ni = 0; ni < 4; ++ni) acc[mi][ni] = z4;

    const float2 z2 = make_float2(0.f, 0.f);
    for (int kc = 0; kc < 8; ++kc) {
        const int kb = kc * 32 + lq * 8;
        bf16x8 bfr[4];
#pragma unroll
        for (int ni = 0; ni < 4; ++ni) {
            const int n = nb + ni * 16 + l16;
            bfr[ni] = *(const bf16x8*)(WcT + (size_t)n * 256 + kb);
        }
        bf16x8 afr[4];
#pragma unroll
        for (int mi = 0; mi < 4; ++mi) {
            const size_t row = m0 + mi * 16 + l16;
            const float* xr = x + row * NF + kb;
            const float2 p0 = *(const float2*)(xr);
            const float2 p1 = (kb + 2 < NF) ? *(const float2*)(xr + 2) : z2;
            const float2 p2 = (kb + 4 < NF) ? *(const float2*)(xr + 4) : z2;
            const float2 p3 = (kb + 6 < NF) ? *(const float2*)(xr + 6) : z2;
            bf16x8 a;
            a[0] = (__bf16)p0.x; a[1] = (__bf16)p0.y;
            a[2] = (__bf16)p1.x; a[3] = (__bf16)p1.y;
            a[4] = (__bf16)p2.x; a[5] = (__bf16)p2.y;
            a[6] = (__bf16)p3.x; a[7] = (__bf16)p3.y;
            afr[mi] = a;
        }
#pragma unroll
        for (int mi = 0; mi < 4; ++mi)
#pragma unroll
            for (int ni = 0; ni < 4; ++ni)
                acc[mi][ni] = __builtin_amdgcn_mfma_f32_16x16x32_bf16(
                    afr[mi], bfr[ni], acc[mi][ni], 0, 0, 0);
    }

#pragma unroll
    for (int ni = 0; ni < 4; ++ni) {
        const int col = nb + ni * 16 + l16;
        if (col < ND) {
            const float bc = biasc[col];
#pragma unroll
            for (int mi = 0; mi < 4; ++mi) {
                const size_t row = m0 + mi * 16 + lq * 4;
#pragma unroll
                for (int r = 0; r < 4; ++r)
                    out[(row + r) * ND + col] = acc[mi][ni][r] + bc;
            }
        }
    }
}

// ============================================================================
extern "C" void kernel_launch(void* const* d_in, const int* in_sizes, int n_in,
                              void* d_out, int out_size, void* d_ws, size_t ws_size,
                              hipStream_t stream) {
    const float* x       = (const float*)d_in[0];
    const float* Wg      = (const float*)d_in[1];
    const float* att_src = (const float*)d_in[2];
    const float* att_dst = (const float*)d_in[3];
    const float* bias_g  = (const float*)d_in[4];
    const float* Wp      = (const float*)d_in[5];
    const float* b_proj  = (const float*)d_in[6];
    float* out = (float*)d_out;
    float* ws  = (float*)d_ws;

    __bf16* WcT    = (__bf16*)ws;                 // 65536 bf16 = 32768 floats
    float* pWcT    = ws + 32768;                  // 8*65536 = 524288
    float* pbias   = pWcT + 8 * 65536;            // 2048
    float* biasc   = pbias + 2048;                // 256
    float* partial = biasc + 256;                 // 512*4096 = 2,097,152
    float* adj     = partial + 512 * 4096;        // 3969
    float* h0      = adj + NC * NC;               // 63,000
    float* as_     = h0 + NC * NHD;               // 252
    float* ad_     = as_ + NC * NH;               // 252
    float* wsm     = ad_ + NC * NH;               // 15,876  (total ~10.9 MB)

    k_wc_part<<<1008, 256, 0, stream>>>(Wg, bias_g, Wp, pWcT, pbias);
    k_wct<<<257, 256, 0, stream>>>(pWcT, pbias, b_proj, WcT, biasc);
    k_main_mfma<<<1008, 256, 0, stream>>>(x, WcT, biasc, out);
    k_adj_partial<<<512, 512, 0, stream>>>(x, partial);
    k_adj_reduce<<<63, 512, 0, stream>>>(partial, adj);
    k_h0asad<<<63, 256, 0, stream>>>(x, Wg, att_src, att_dst, h0, as_, ad_);
    k_mask_soft<<<1, 256, 0, stream>>>(adj, as_, ad_, wsm);
    k_out0<<<63, 512, 0, stream>>>(wsm, h0, bias_g, Wp, b_proj, out);
}

// Round 5
// 231.347 us; speedup vs baseline: 2.1818x; 1.1853x over previous
//
#include <hip/hip_runtime.h>
#include <math.h>

#define NB 1024
#define NC 63
#define NF 250
#define NH 4
#define ND 250
#define NHD 1000

typedef __bf16 bf16x8 __attribute__((ext_vector_type(8)));
typedef float f32x4 __attribute__((ext_vector_type(4)));

// ============================================================================
// k_adj_mfma: per-batch 64x64 gram via bf16 MFMA with hi/lo split.
//   x_b (63x250 fp32) -> Xh + Xl (bf16 planes in LDS, row padded to 256,
//   XOR-swizzled k^=(row&7)<<3 so 512B-stride fragment reads are
//   conflict-free). Row 63 = ones => G[:,63] = row sums S; diag => SS.
//   G = Hh.Hh^T + Hh.Hl^T + Hl.Hh^T (lo*lo dropped, ~2^-18 rel).
//   Per batch fixup: adj += (G - F*m_i*m_j)*s_i*s_j  (ddof=1 std).
// grid 256 x 256 thr (4 waves); each block does 4 batches serially.
// Wave w owns tile-row w: tiles (w, 0..3) of 16x16; K handled inside MFMA
// (no cross-wave reduce). 3 barriers/batch.
// ============================================================================
__global__ __launch_bounds__(256) void k_adj_mfma(const float* __restrict__ x,
                                                  float* __restrict__ partial) {
    __shared__ __align__(16) __bf16 Xh[64 * 256];   // 32 KB
    __shared__ __align__(16) __bf16 Xl[64 * 256];   // 32 KB
    __shared__ float sS[64], ssS[64], meanv[64], sclv[64];
    const int t = threadIdx.x;
    const int w = t >> 6, l = t & 63;
    const int l16 = l & 15, lq = l >> 4;
    const int swz = (l16 & 7) << 3;      // fragment-read swizzle (row&7 == l16&7)

    // ones row (row 63) in hi plane, zeros in lo plane — set once.
    {
        const int kz = t ^ ((63 & 7) << 3);   // swizzled position of element t
        Xh[63 * 256 + kz] = (__bf16)1.0f;
        Xl[63 * 256 + kz] = (__bf16)0.0f;
    }

    float adjacc[4][4];
#pragma unroll
    for (int ni = 0; ni < 4; ++ni)
#pragma unroll
        for (int r = 0; r < 4; ++r) adjacc[ni][r] = 0.f;

    for (int bb = 0; bb < 4; ++bb) {
        const float* xb = x + (size_t)(blockIdx.x * 4 + bb) * (NC * NF);
        // ---- staging: thread owns (row, k-octet) units; b128 swizzled writes.
        // 2016 units = 63 rows x 32 octets (octet 31 zero-padded past k=249).
#pragma unroll
        for (int it = 0; it < 8; ++it) {
            const int u = it * 256 + t;
            if (u < 2016) {
                const int row = u >> 5;
                const int ko = (u & 31) << 3;
                const float* src = xb + row * NF + ko;
                float v[8];
#pragma unroll
                for (int q = 0; q < 4; ++q) {
                    if (ko + q * 2 < NF) {
                        const float2 p = *(const float2*)(src + q * 2);
                        v[2 * q] = p.x; v[2 * q + 1] = p.y;
                    } else { v[2 * q] = 0.f; v[2 * q + 1] = 0.f; }
                }
                bf16x8 h, lo_;
#pragma unroll
                for (int j = 0; j < 8; ++j) {
                    h[j] = (__bf16)v[j];
                    lo_[j] = (__bf16)(v[j] - (float)h[j]);
                }
                const int kS = ko ^ ((row & 7) << 3);
                *(bf16x8*)&Xh[row * 256 + kS] = h;
                *(bf16x8*)&Xl[row * 256 + kS] = lo_;
            }
        }
        __syncthreads();   // staging complete -> MFMA may read

        // ---- MFMA: G tile-row w. acc[ni] = 16x16 tile (w, ni).
        f32x4 acc[4];
        const f32x4 z4 = {0.f, 0.f, 0.f, 0.f};
#pragma unroll
        for (int ni = 0; ni < 4; ++ni) acc[ni] = z4;
        const int arow = 16 * w + l16;
#pragma unroll
        for (int kc = 0; kc < 8; ++kc) {
            const int kb = (kc * 32 + lq * 8) ^ swz;
            const bf16x8 ah = *(const bf16x8*)&Xh[arow * 256 + kb];
            const bf16x8 al = *(const bf16x8*)&Xl[arow * 256 + kb];
#pragma unroll
            for (int ni = 0; ni < 4; ++ni) {
                const int brow = 16 * ni + l16;
                const bf16x8 bh = *(const bf16x8*)&Xh[brow * 256 + kb];
                const bf16x8 bl = *(const bf16x8*)&Xl[brow * 256 + kb];
                acc[ni] = __builtin_amdgcn_mfma_f32_16x16x32_bf16(ah, bh, acc[ni], 0, 0, 0);
                acc[ni] = __builtin_amdgcn_mfma_f32_16x16x32_bf16(ah, bl, acc[ni], 0, 0, 0);
                acc[ni] = __builtin_amdgcn_mfma_f32_16x16x32_bf16(al, bh, acc[ni], 0, 0, 0);
            }
        }

        // ---- extract moments: col 63 of G = S (tile ni=3, lanes l16==15);
        //      diag of G = SS (tile ni=w, lanes with l16>>2 == lq).
        if (l16 == 15) {
#pragma unroll
            for (int r = 0; r < 4; ++r) sS[16 * w + lq * 4 + r] = acc[3][r];
        }
        if ((l16 >> 2) == lq) ssS[16 * w + l16] = acc[w][l16 & 3];
        __syncthreads();
        if (t < 64) {
            const float S = sS[t], SSv = ssS[t];
            float m = S * (1.f / (float)NF);
            const float var = (SSv - S * S * (1.f / (float)NF)) * (1.f / (float)(NF - 1));
            float sc = 1.f / (sqrtf(var) + 1e-8f);
            if (t >= NC) { m = 0.f; sc = 0.f; }
            meanv[t] = m; sclv[t] = sc;
        }
        __syncthreads();

        // ---- fixup + accumulate (D layout: col = l16, row = lq*4 + r)
        float mr[4], sr[4];
#pragma unroll
        for (int r = 0; r < 4; ++r) {
            const int row = 16 * w + lq * 4 + r;
            mr[r] = meanv[row]; sr[r] = sclv[row];
        }
#pragma unroll
        for (int ni = 0; ni < 4; ++ni) {
            const float mc = meanv[16 * ni + l16];
            const float sc = sclv[16 * ni + l16];
#pragma unroll
            for (int r = 0; r < 4; ++r)
                adjacc[ni][r] += (acc[ni][r] - (float)NF * mr[r] * mc) * sr[r] * sc;
        }
        // no barrier needed here: next staging writes Xh/Xl, all MFMA reads
        // finished before the post-extract barrier above.
    }

    // ---- write block partial [64][64]
#pragma unroll
    for (int ni = 0; ni < 4; ++ni)
#pragma unroll
        for (int r = 0; r < 4; ++r) {
            const int row = 16 * w + lq * 4 + r;
            const int col = 16 * ni + l16;
            partial[(size_t)blockIdx.x * 4096 + row * 64 + col] = adjacc[ni][r];
        }
}

// ============================================================================
// Reduce 256 partials -> adj (63x63). grid 63 rows x 512 thr.
// ============================================================================
__global__ __launch_bounds__(512) void k_adj_reduce(const float* __restrict__ partial,
                                                    float* __restrict__ adj) {
    __shared__ float red[8][64];
    const int row = blockIdx.x, t = threadIdx.x;
    const int c = t & 63, g = t >> 6;
    float s = 0.f;
    const float* p = partial + (size_t)(g * 32) * 4096 + row * 64 + c;
#pragma unroll 8
    for (int i = 0; i < 32; ++i) s += p[(size_t)i * 4096];
    red[g][c] = s;
    __syncthreads();
    if (t < NC) {
        float tot = 0.f;
#pragma unroll
        for (int gg = 0; gg < 8; ++gg) tot += red[gg][t];
        adj[row * NC + t] = tot * (1.f / ((float)NF * (float)NB));
    }
}

// ============================================================================
// h0 = x[0] @ W_gat  (63 x 1000) + fused a_s/a_d per-head dots. grid 63.
// ============================================================================
__global__ __launch_bounds__(256) void k_h0asad(const float* __restrict__ x,
                                                const float* __restrict__ Wg,
                                                const float* __restrict__ att_src,
                                                const float* __restrict__ att_dst,
                                                float* __restrict__ h0,
                                                float* __restrict__ as_,
                                                float* __restrict__ ad_) {
    __shared__ float xrow[NF];
    __shared__ float y[NHD];
    __shared__ float red[256], red2[256];
    const int c = blockIdx.x, t = threadIdx.x;
    if (t < NF) xrow[t] = x[c * NF + t];
    __syncthreads();
    int n0 = t, n1 = t + 256, n2 = t + 512;
    int n3 = (t + 768 < NHD) ? t + 768 : NHD - 1;
    float acc0 = 0, acc1 = 0, acc2 = 0, acc3 = 0;
    for (int f = 0; f < NF; ++f) {
        float xv = xrow[f];
        const float* wr = Wg + (size_t)f * NHD;
        acc0 += xv * wr[n0];
        acc1 += xv * wr[n1];
        acc2 += xv * wr[n2];
        acc3 += xv * wr[n3];
    }
    h0[c * NHD + n0] = acc0; y[n0] = acc0;
    h0[c * NHD + n1] = acc1; y[n1] = acc1;
    h0[c * NHD + n2] = acc2; y[n2] = acc2;
    if (t + 768 < NHD) { h0[c * NHD + n3] = acc3; y[n3] = acc3; }
    __syncthreads();
    for (int h = 0; h < NH; ++h) {
        float vs = 0.f, vd = 0.f;
        if (t < ND) {
            float yv = y[h * ND + t];
            vs = yv * att_src[h * ND + t];
            vd = yv * att_dst[h * ND + t];
        }
        red[t] = vs; red2[t] = vd;
        __syncthreads();
        if (t < 128) { red[t] += red[t + 128]; red2[t] += red2[t + 128]; }
        __syncthreads();
        if (t < 64) { red[t] += red[t + 64]; red2[t] += red2[t + 64]; }
        __syncthreads();
        if (t < 64) {
            float r = red[t], r2 = red2[t];
#pragma unroll
            for (int off = 32; off >= 1; off >>= 1) {
                r += __shfl_down(r, off);
                r2 += __shfl_down(r2, off);
            }
            if (t == 0) { as_[c * NH + h] = r; ad_[c * NH + h] = r2; }
        }
        __syncthreads();
    }
}

// ============================================================================
// Fused threshold + masked softmax, all staged in LDS (R4 version).
// ============================================================================
__global__ __launch_bounds__(256) void k_mask_soft(const float* __restrict__ adj,
                                                   const float* __restrict__ as_,
                                                   const float* __restrict__ ad_,
                                                   float* __restrict__ w) {
    __shared__ float adjS[NC * NC];
    __shared__ float wS[NC * NC * NH];
    __shared__ float asS[NC * NH], adS[NC * NH];
    __shared__ float th[NC];
    const int t = threadIdx.x;
    for (int e = t; e < NC * NC; e += 256) adjS[e] = adj[e];
    if (t < NC * NH) { asS[t] = as_[t]; adS[t] = ad_[t]; }
    __syncthreads();
    if (t < NC) {
        float prev = INFINITY;
        int krem = 8;                       // TOP_K
        float v_th = -INFINITY;
        for (int iter = 0; iter < 8; ++iter) {
            float vmax = -INFINITY; int cnt = 0;
            for (int j = 0; j < NC; ++j) {
                float v = adjS[t * NC + j];
                if (v < prev) {
                    if (v > vmax) { vmax = v; cnt = 1; }
                    else if (v == vmax) cnt++;
                }
            }
            if (cnt >= krem) { v_th = vmax; break; }
            krem -= cnt; prev = vmax;
        }
        th[t] = v_th;
    }
    __syncthreads();
    if (t < NC * NH) {
        const int j = t >> 2, h = t & 3;
        const float adv = adS[j * NH + h];
        float m = -INFINITY;
        for (int i = 0; i < NC; ++i) {
            float a = adjS[i * NC + j];
            bool msk = (i == j) || ((a >= th[i]) && (a != 0.f));
            if (msk) {
                float e = asS[i * NH + h] + adv;
                e = e > 0.f ? e : 0.2f * e;
                m = fmaxf(m, e);
            }
        }
        float ssum = 0.f;
        for (int i = 0; i < NC; ++i) {
            float a = adjS[i * NC + j];
            bool msk = (i == j) || ((a >= th[i]) && (a != 0.f));
            float wv = 0.f;
            if (msk) {
                float e = asS[i * NH + h] + adv;
                e = e > 0.f ? e : 0.2f * e;
                wv = __expf(e - m);
                ssum += wv;
            }
            wS[(i * NC + j) * NH + h] = wv;
        }
        const float inv = 1.f / ssum;
        for (int i = 0; i < NC; ++i)
            wS[(i * NC + j) * NH + h] *= inv;
    }
    __syncthreads();
    for (int e = t; e < NC * NC * NH; e += 256) w[e] = wS[e];
}

// ============================================================================
// b=0 rows: att0 + projection. grid 63 x 512.
// ============================================================================
__global__ __launch_bounds__(512) void k_out0(const float* __restrict__ w,
                                              const float* __restrict__ h0,
                                              const float* __restrict__ bias_gat,
                                              const float* __restrict__ Wp,
                                              const float* __restrict__ b_proj,
                                              float* __restrict__ out) {
    __shared__ float wcol[NC * NH];
    __shared__ float y[NHD];
    __shared__ float psum[2][256];
    const int j = blockIdx.x, t = threadIdx.x;
    if (t < NC * NH) {
        int i = t >> 2, h = t & 3;
        wcol[t] = w[(i * NC + j) * NH + h];
    }
    __syncthreads();
    for (int n = t; n < NHD; n += 512) {
        int h = n / ND;
        float acc = 0.f;
        for (int i = 0; i < NC; ++i)
            acc += wcol[i * NH + h] * h0[i * NHD + n];
        y[n] = acc + bias_gat[n];
    }
    __syncthreads();
    const int q = t >> 8, col = t & 255;
    float acc = 0.f;
    if (col < ND) {
        for (int k = q * 500; k < q * 500 + 500; ++k)
            acc += y[k] * Wp[(size_t)k * ND + col];
    }
    psum[q][col] = acc;
    __syncthreads();
    if (t < ND) out[j * ND + t] = psum[0][t] + psum[1][t] + b_proj[t];
}

// ============================================================================
// Wc split-K x8 partials, stored TRANSPOSED pWcT[kq][n][256f].
// ============================================================================
__global__ __launch_bounds__(256) void k_wc_part(const float* __restrict__ Wg,
                                                 const float* __restrict__ bias_gat,
                                                 const float* __restrict__ Wp,
                                                 float* __restrict__ pWcT,
                                                 float* __restrict__ pbias) {
    __shared__ float rows[250];
    const int b = blockIdx.x, t = threadIdx.x;
    if (b < 1000) {
        const int fb = (b >> 3) * 2, kq = b & 7;
        if (t < 250)
            rows[t] = Wg[(size_t)(fb + t / 125) * NHD + kq * 125 + (t % 125)];
        __syncthreads();
        if (t < ND) {
            float a0 = 0.f, a1 = 0.f;
            const float* wp = Wp + (size_t)(kq * 125) * ND + t;
            for (int k = 0; k < 125; ++k) {
                float wv = wp[(size_t)k * ND];
                a0 += rows[k] * wv;
                a1 += rows[125 + k] * wv;
            }
            pWcT[(size_t)kq * 65536 + (size_t)t * 256 + fb] = a0;
            pWcT[(size_t)kq * 65536 + (size_t)t * 256 + fb + 1] = a1;
        }
    } else {
        const int kq = b - 1000;
        if (t < ND) {
            float acc = 0.f;
            for (int k = kq * 125; k < kq * 125 + 125; ++k)
                acc += bias_gat[k] * Wp[(size_t)k * ND + t];
            pbias[kq * 256 + t] = acc;
        }
    }
}

// ============================================================================
// Combine: WcT[n][f] bf16 (padded [256][256]); block 256 does biasc.
// ============================================================================
__global__ __launch_bounds__(256) void k_wct(const float* __restrict__ pWcT,
                                             const float* __restrict__ pbias,
                                             const float* __restrict__ b_proj,
                                             __bf16* __restrict__ WcT,
                                             float* __restrict__ biasc) {
    const int n = blockIdx.x, t = threadIdx.x;
    if (n < 256) {
        float v = 0.f;
        if (n < ND && t < NF) {
            size_t e = (size_t)n * 256 + t;
#pragma unroll
            for (int kq = 0; kq < 8; ++kq) v += pWcT[(size_t)kq * 65536 + e];
        }
        WcT[n * 256 + t] = (__bf16)v;
    } else {
        if (t < ND) {
            float v = 0.f;
#pragma unroll
            for (int kq = 0; kq < 8; ++kq) v += pbias[kq * 256 + t];
            biasc[t] = v + b_proj[t];
        }
    }
}

// ============================================================================
// MAIN: out = x @ Wc + biasc via bf16 MFMA, zero LDS (unchanged).
// ============================================================================
__global__ __launch_bounds__(256) void k_main_mfma(const float* __restrict__ x,
                                                   const __bf16* __restrict__ WcT,
                                                   const float* __restrict__ biasc,
                                                   float* __restrict__ out) {
    const int t = threadIdx.x;
    const int w = t >> 6;
    const int l = t & 63;
    const int l16 = l & 15, lq = l >> 4;
    const size_t m0 = (size_t)blockIdx.x * 64;
    const int nb = w * 64;

    f32x4 acc[4][4];
    const f32x4 z4 = {0.f, 0.f, 0.f, 0.f};
#pragma unroll
    for (int mi = 0; mi < 4; ++mi)
#pragma unroll
        for (int ni = 0; ni < 4; ++ni) acc[mi][ni] = z4;

    const float2 z2 = make_float2(0.f, 0.f);
    for (int kc = 0; kc < 8; ++kc) {
        const int kb = kc * 32 + lq * 8;
        bf16x8 bfr[4];
#pragma unroll
        for (int ni = 0; ni < 4; ++ni) {
            const int n = nb + ni * 16 + l16;
            bfr[ni] = *(const bf16x8*)(WcT + (size_t)n * 256 + kb);
        }
        bf16x8 afr[4];
#pragma unroll
        for (int mi = 0; mi < 4; ++mi) {
            const size_t row = m0 + mi * 16 + l16;
            const float* xr = x + row * NF + kb;
            const float2 p0 = *(const float2*)(xr);
            const float2 p1 = (kb + 2 < NF) ? *(const float2*)(xr + 2) : z2;
            const float2 p2 = (kb + 4 < NF) ? *(const float2*)(xr + 4) : z2;
            const float2 p3 = (kb + 6 < NF) ? *(const float2*)(xr + 6) : z2;
            bf16x8 a;
            a[0] = (__bf16)p0.x; a[1] = (__bf16)p0.y;
            a[2] = (__bf16)p1.x; a[3] = (__bf16)p1.y;
            a[4] = (__bf16)p2.x; a[5] = (__bf16)p2.y;
            a[6] = (__bf16)p3.x; a[7] = (__bf16)p3.y;
            afr[mi] = a;
        }
#pragma unroll
        for (int mi = 0; mi < 4; ++mi)
#pragma unroll
            for (int ni = 0; ni < 4; ++ni)
                acc[mi][ni] = __builtin_amdgcn_mfma_f32_16x16x32_bf16(
                    afr[mi], bfr[ni], acc[mi][ni], 0, 0, 0);
    }

#pragma unroll
    for (int ni = 0; ni < 4; ++ni) {
        const int col = nb + ni * 16 + l16;
        if (col < ND) {
            const float bc = biasc[col];
#pragma unroll
            for (int mi = 0; mi < 4; ++mi) {
                const size_t row = m0 + mi * 16 + lq * 4;
#pragma unroll
                for (int r = 0; r < 4; ++r)
                    out[(row + r) * ND + col] = acc[mi][ni][r] + bc;
            }
        }
    }
}

// ============================================================================
extern "C" void kernel_launch(void* const* d_in, const int* in_sizes, int n_in,
                              void* d_out, int out_size, void* d_ws, size_t ws_size,
                              hipStream_t stream) {
    const float* x       = (const float*)d_in[0];
    const float* Wg      = (const float*)d_in[1];
    const float* att_src = (const float*)d_in[2];
    const float* att_dst = (const float*)d_in[3];
    const float* bias_g  = (const float*)d_in[4];
    const float* Wp      = (const float*)d_in[5];
    const float* b_proj  = (const float*)d_in[6];
    float* out = (float*)d_out;
    float* ws  = (float*)d_ws;

    __bf16* WcT    = (__bf16*)ws;                 // 65536 bf16 = 32768 floats
    float* pWcT    = ws + 32768;                  // 8*65536 = 524288
    float* pbias   = pWcT + 8 * 65536;            // 2048
    float* biasc   = pbias + 2048;                // 256
    float* partial = biasc + 256;                 // 256*4096 = 1,048,576
    float* adj     = partial + 256 * 4096;        // 3969
    float* h0      = adj + NC * NC;               // 63,000
    float* as_     = h0 + NC * NHD;               // 252
    float* ad_     = as_ + NC * NH;               // 252
    float* wsm     = ad_ + NC * NH;               // 15,876  (total ~6.7 MB)

    k_wc_part<<<1008, 256, 0, stream>>>(Wg, bias_g, Wp, pWcT, pbias);
    k_wct<<<257, 256, 0, stream>>>(pWcT, pbias, b_proj, WcT, biasc);
    k_main_mfma<<<1008, 256, 0, stream>>>(x, WcT, biasc, out);
    k_adj_mfma<<<256, 256, 0, stream>>>(x, partial);
    k_adj_reduce<<<63, 512, 0, stream>>>(partial, adj);
    k_h0asad<<<63, 256, 0, stream>>>(x, Wg, att_src, att_dst, h0, as_, ad_);
    k_mask_soft<<<1, 256, 0, stream>>>(adj, as_, ad_, wsm);
    k_out0<<<63, 512, 0, stream>>>(wsm, h0, bias_g, Wp, b_proj, out);
}

// Round 6
// 214.345 us; speedup vs baseline: 2.3549x; 1.0793x over previous
//
#include <hip/hip_runtime.h>
#include <math.h>

#define NB 1024
#define NC 63
#define NF 250
#define NH 4
#define ND 250
#define NHD 1000

typedef __bf16 bf16x8 __attribute__((ext_vector_type(8)));
typedef float f32x4 __attribute__((ext_vector_type(4)));

// ============================================================================
// k_adj_mfma: per-batch 64x64 gram via bf16 MFMA with hi/lo split (unchanged).
// ============================================================================
__global__ __launch_bounds__(256) void k_adj_mfma(const float* __restrict__ x,
                                                  float* __restrict__ partial) {
    __shared__ __align__(16) __bf16 Xh[64 * 256];   // 32 KB
    __shared__ __align__(16) __bf16 Xl[64 * 256];   // 32 KB
    __shared__ float sS[64], ssS[64], meanv[64], sclv[64];
    const int t = threadIdx.x;
    const int w = t >> 6, l = t & 63;
    const int l16 = l & 15, lq = l >> 4;
    const int swz = (l16 & 7) << 3;

    {
        const int kz = t ^ ((63 & 7) << 3);
        Xh[63 * 256 + kz] = (__bf16)1.0f;
        Xl[63 * 256 + kz] = (__bf16)0.0f;
    }

    float adjacc[4][4];
#pragma unroll
    for (int ni = 0; ni < 4; ++ni)
#pragma unroll
        for (int r = 0; r < 4; ++r) adjacc[ni][r] = 0.f;

    for (int bb = 0; bb < 4; ++bb) {
        const float* xb = x + (size_t)(blockIdx.x * 4 + bb) * (NC * NF);
#pragma unroll
        for (int it = 0; it < 8; ++it) {
            const int u = it * 256 + t;
            if (u < 2016) {
                const int row = u >> 5;
                const int ko = (u & 31) << 3;
                const float* src = xb + row * NF + ko;
                float v[8];
#pragma unroll
                for (int q = 0; q < 4; ++q) {
                    if (ko + q * 2 < NF) {
                        const float2 p = *(const float2*)(src + q * 2);
                        v[2 * q] = p.x; v[2 * q + 1] = p.y;
                    } else { v[2 * q] = 0.f; v[2 * q + 1] = 0.f; }
                }
                bf16x8 h, lo_;
#pragma unroll
                for (int j = 0; j < 8; ++j) {
                    h[j] = (__bf16)v[j];
                    lo_[j] = (__bf16)(v[j] - (float)h[j]);
                }
                const int kS = ko ^ ((row & 7) << 3);
                *(bf16x8*)&Xh[row * 256 + kS] = h;
                *(bf16x8*)&Xl[row * 256 + kS] = lo_;
            }
        }
        __syncthreads();

        f32x4 acc[4];
        const f32x4 z4 = {0.f, 0.f, 0.f, 0.f};
#pragma unroll
        for (int ni = 0; ni < 4; ++ni) acc[ni] = z4;
        const int arow = 16 * w + l16;
#pragma unroll
        for (int kc = 0; kc < 8; ++kc) {
            const int kb = (kc * 32 + lq * 8) ^ swz;
            const bf16x8 ah = *(const bf16x8*)&Xh[arow * 256 + kb];
            const bf16x8 al = *(const bf16x8*)&Xl[arow * 256 + kb];
#pragma unroll
            for (int ni = 0; ni < 4; ++ni) {
                const int brow = 16 * ni + l16;
                const bf16x8 bh = *(const bf16x8*)&Xh[brow * 256 + kb];
                const bf16x8 bl = *(const bf16x8*)&Xl[brow * 256 + kb];
                acc[ni] = __builtin_amdgcn_mfma_f32_16x16x32_bf16(ah, bh, acc[ni], 0, 0, 0);
                acc[ni] = __builtin_amdgcn_mfma_f32_16x16x32_bf16(ah, bl, acc[ni], 0, 0, 0);
                acc[ni] = __builtin_amdgcn_mfma_f32_16x16x32_bf16(al, bh, acc[ni], 0, 0, 0);
            }
        }

        if (l16 == 15) {
#pragma unroll
            for (int r = 0; r < 4; ++r) sS[16 * w + lq * 4 + r] = acc[3][r];
        }
        if ((l16 >> 2) == lq) ssS[16 * w + l16] = acc[w][l16 & 3];
        __syncthreads();
        if (t < 64) {
            const float S = sS[t], SSv = ssS[t];
            float m = S * (1.f / (float)NF);
            const float var = (SSv - S * S * (1.f / (float)NF)) * (1.f / (float)(NF - 1));
            float sc = 1.f / (sqrtf(var) + 1e-8f);
            if (t >= NC) { m = 0.f; sc = 0.f; }
            meanv[t] = m; sclv[t] = sc;
        }
        __syncthreads();

        float mr[4], sr[4];
#pragma unroll
        for (int r = 0; r < 4; ++r) {
            const int row = 16 * w + lq * 4 + r;
            mr[r] = meanv[row]; sr[r] = sclv[row];
        }
#pragma unroll
        for (int ni = 0; ni < 4; ++ni) {
            const float mc = meanv[16 * ni + l16];
            const float sc = sclv[16 * ni + l16];
#pragma unroll
            for (int r = 0; r < 4; ++r)
                adjacc[ni][r] += (acc[ni][r] - (float)NF * mr[r] * mc) * sr[r] * sc;
        }
    }

#pragma unroll
    for (int ni = 0; ni < 4; ++ni)
#pragma unroll
        for (int r = 0; r < 4; ++r) {
            const int row = 16 * w + lq * 4 + r;
            const int col = 16 * ni + l16;
            partial[(size_t)blockIdx.x * 4096 + row * 64 + col] = adjacc[ni][r];
        }
}

// ============================================================================
// Reduce 256 partials -> adj (63x63). grid 63 rows x 512 thr.
// ============================================================================
__global__ __launch_bounds__(512) void k_adj_reduce(const float* __restrict__ partial,
                                                    float* __restrict__ adj) {
    __shared__ float red[8][64];
    const int row = blockIdx.x, t = threadIdx.x;
    const int c = t & 63, g = t >> 6;
    float s = 0.f;
    const float* p = partial + (size_t)(g * 32) * 4096 + row * 64 + c;
#pragma unroll 8
    for (int i = 0; i < 32; ++i) s += p[(size_t)i * 4096];
    red[g][c] = s;
    __syncthreads();
    if (t < NC) {
        float tot = 0.f;
#pragma unroll
        for (int gg = 0; gg < 8; ++gg) tot += red[gg][t];
        adj[row * NC + t] = tot * (1.f / ((float)NF * (float)NB));
    }
}

// ============================================================================
// h0 = x[0] @ W_gat  (63 x 1000) + fused a_s/a_d per-head dots. grid 63.
// ============================================================================
__global__ __launch_bounds__(256) void k_h0asad(const float* __restrict__ x,
                                                const float* __restrict__ Wg,
                                                const float* __restrict__ att_src,
                                                const float* __restrict__ att_dst,
                                                float* __restrict__ h0,
                                                float* __restrict__ as_,
                                                float* __restrict__ ad_) {
    __shared__ float xrow[NF];
    __shared__ float y[NHD];
    __shared__ float red[256], red2[256];
    const int c = blockIdx.x, t = threadIdx.x;
    if (t < NF) xrow[t] = x[c * NF + t];
    __syncthreads();
    int n0 = t, n1 = t + 256, n2 = t + 512;
    int n3 = (t + 768 < NHD) ? t + 768 : NHD - 1;
    float acc0 = 0, acc1 = 0, acc2 = 0, acc3 = 0;
    for (int f = 0; f < NF; ++f) {
        float xv = xrow[f];
        const float* wr = Wg + (size_t)f * NHD;
        acc0 += xv * wr[n0];
        acc1 += xv * wr[n1];
        acc2 += xv * wr[n2];
        acc3 += xv * wr[n3];
    }
    h0[c * NHD + n0] = acc0; y[n0] = acc0;
    h0[c * NHD + n1] = acc1; y[n1] = acc1;
    h0[c * NHD + n2] = acc2; y[n2] = acc2;
    if (t + 768 < NHD) { h0[c * NHD + n3] = acc3; y[n3] = acc3; }
    __syncthreads();
    for (int h = 0; h < NH; ++h) {
        float vs = 0.f, vd = 0.f;
        if (t < ND) {
            float yv = y[h * ND + t];
            vs = yv * att_src[h * ND + t];
            vd = yv * att_dst[h * ND + t];
        }
        red[t] = vs; red2[t] = vd;
        __syncthreads();
        if (t < 128) { red[t] += red[t + 128]; red2[t] += red2[t + 128]; }
        __syncthreads();
        if (t < 64) { red[t] += red[t + 64]; red2[t] += red2[t + 64]; }
        __syncthreads();
        if (t < 64) {
            float r = red[t], r2 = red2[t];
#pragma unroll
            for (int off = 32; off >= 1; off >>= 1) {
                r += __shfl_down(r, off);
                r2 += __shfl_down(r2, off);
            }
            if (t == 0) { as_[c * NH + h] = r; ad_[c * NH + h] = r2; }
        }
        __syncthreads();
    }
}

// ============================================================================
// Fused threshold + masked softmax, all staged in LDS.
// ============================================================================
__global__ __launch_bounds__(256) void k_mask_soft(const float* __restrict__ adj,
                                                   const float* __restrict__ as_,
                                                   const float* __restrict__ ad_,
                                                   float* __restrict__ w) {
    __shared__ float adjS[NC * NC];
    __shared__ float wS[NC * NC * NH];
    __shared__ float asS[NC * NH], adS[NC * NH];
    __shared__ float th[NC];
    const int t = threadIdx.x;
    for (int e = t; e < NC * NC; e += 256) adjS[e] = adj[e];
    if (t < NC * NH) { asS[t] = as_[t]; adS[t] = ad_[t]; }
    __syncthreads();
    if (t < NC) {
        float prev = INFINITY;
        int krem = 8;                       // TOP_K
        float v_th = -INFINITY;
        for (int iter = 0; iter < 8; ++iter) {
            float vmax = -INFINITY; int cnt = 0;
            for (int j = 0; j < NC; ++j) {
                float v = adjS[t * NC + j];
                if (v < prev) {
                    if (v > vmax) { vmax = v; cnt = 1; }
                    else if (v == vmax) cnt++;
                }
            }
            if (cnt >= krem) { v_th = vmax; break; }
            krem -= cnt; prev = vmax;
        }
        th[t] = v_th;
    }
    __syncthreads();
    if (t < NC * NH) {
        const int j = t >> 2, h = t & 3;
        const float adv = adS[j * NH + h];
        float m = -INFINITY;
        for (int i = 0; i < NC; ++i) {
            float a = adjS[i * NC + j];
            bool msk = (i == j) || ((a >= th[i]) && (a != 0.f));
            if (msk) {
                float e = asS[i * NH + h] + adv;
                e = e > 0.f ? e : 0.2f * e;
                m = fmaxf(m, e);
            }
        }
        float ssum = 0.f;
        for (int i = 0; i < NC; ++i) {
            float a = adjS[i * NC + j];
            bool msk = (i == j) || ((a >= th[i]) && (a != 0.f));
            float wv = 0.f;
            if (msk) {
                float e = asS[i * NH + h] + adv;
                e = e > 0.f ? e : 0.2f * e;
                wv = __expf(e - m);
                ssum += wv;
            }
            wS[(i * NC + j) * NH + h] = wv;
        }
        const float inv = 1.f / ssum;
        for (int i = 0; i < NC; ++i)
            wS[(i * NC + j) * NH + h] *= inv;
    }
    __syncthreads();
    for (int e = t; e < NC * NC * NH; e += 256) w[e] = wS[e];
}

// ============================================================================
// b=0 rows: att0 + projection. grid 63 x 512.
// ============================================================================
__global__ __launch_bounds__(512) void k_out0(const float* __restrict__ w,
                                              const float* __restrict__ h0,
                                              const float* __restrict__ bias_gat,
                                              const float* __restrict__ Wp,
                                              const float* __restrict__ b_proj,
                                              float* __restrict__ out) {
    __shared__ float wcol[NC * NH];
    __shared__ float y[NHD];
    __shared__ float psum[2][256];
    const int j = blockIdx.x, t = threadIdx.x;
    if (t < NC * NH) {
        int i = t >> 2, h = t & 3;
        wcol[t] = w[(i * NC + j) * NH + h];
    }
    __syncthreads();
    for (int n = t; n < NHD; n += 512) {
        int h = n / ND;
        float acc = 0.f;
        for (int i = 0; i < NC; ++i)
            acc += wcol[i * NH + h] * h0[i * NHD + n];
        y[n] = acc + bias_gat[n];
    }
    __syncthreads();
    const int q = t >> 8, col = t & 255;
    float acc = 0.f;
    if (col < ND) {
        for (int k = q * 500; k < q * 500 + 500; ++k)
            acc += y[k] * Wp[(size_t)k * ND + col];
    }
    psum[q][col] = acc;
    __syncthreads();
    if (t < ND) out[j * ND + t] = psum[0][t] + psum[1][t] + b_proj[t];
}

// ============================================================================
// Wc split-K x8 partials, stored TRANSPOSED pWcT[kq][n][256f].
// ============================================================================
__global__ __launch_bounds__(256) void k_wc_part(const float* __restrict__ Wg,
                                                 const float* __restrict__ bias_gat,
                                                 const float* __restrict__ Wp,
                                                 float* __restrict__ pWcT,
                                                 float* __restrict__ pbias) {
    __shared__ float rows[250];
    const int b = blockIdx.x, t = threadIdx.x;
    if (b < 1000) {
        const int fb = (b >> 3) * 2, kq = b & 7;
        if (t < 250)
            rows[t] = Wg[(size_t)(fb + t / 125) * NHD + kq * 125 + (t % 125)];
        __syncthreads();
        if (t < ND) {
            float a0 = 0.f, a1 = 0.f;
            const float* wp = Wp + (size_t)(kq * 125) * ND + t;
            for (int k = 0; k < 125; ++k) {
                float wv = wp[(size_t)k * ND];
                a0 += rows[k] * wv;
                a1 += rows[125 + k] * wv;
            }
            pWcT[(size_t)kq * 65536 + (size_t)t * 256 + fb] = a0;
            pWcT[(size_t)kq * 65536 + (size_t)t * 256 + fb + 1] = a1;
        }
    } else {
        const int kq = b - 1000;
        if (t < ND) {
            float acc = 0.f;
            for (int k = kq * 125; k < kq * 125 + 125; ++k)
                acc += bias_gat[k] * Wp[(size_t)k * ND + t];
            pbias[kq * 256 + t] = acc;
        }
    }
}

// ============================================================================
// Combine: WcT[n][f] bf16 (padded [256][256]); block 256 does biasc.
// ============================================================================
__global__ __launch_bounds__(256) void k_wct(const float* __restrict__ pWcT,
                                             const float* __restrict__ pbias,
                                             const float* __restrict__ b_proj,
                                             __bf16* __restrict__ WcT,
                                             float* __restrict__ biasc) {
    const int n = blockIdx.x, t = threadIdx.x;
    if (n < 256) {
        float v = 0.f;
        if (n < ND && t < NF) {
            size_t e = (size_t)n * 256 + t;
#pragma unroll
            for (int kq = 0; kq < 8; ++kq) v += pWcT[(size_t)kq * 65536 + e];
        }
        WcT[n * 256 + t] = (__bf16)v;
    } else {
        if (t < ND) {
            float v = 0.f;
#pragma unroll
            for (int kq = 0; kq < 8; ++kq) v += pbias[kq * 256 + t];
            biasc[t] = v + b_proj[t];
        }
    }
}

// ============================================================================
// MAIN v3: out = x @ Wc + biasc via bf16 MFMA.
// Fixes R5's address-divergence stall (83us @ 1.5TB/s, MfmaUtil 3.7%):
//  - B (WcT) fragments hoisted to 128 VGPRs ONCE per block (the scattered
//    512B-stride loads happen 1x/block instead of 8x/tile/wave).
//  - A staged through LDS: the 64-row tile is a CONTIGUOUS 62.5KB slab of x;
//    coalesced float2 reads -> bf16 cvt -> swizzled ds_write_b128 [64][256]
//    (k_adj_mfma's proven pattern); fragments via XOR-swizzled ds_read_b128.
//  - grid 504 x 2 M-tiles per block (amortize B preload); 4 waves split N.
//  - epilogue: ni innermost so each lane covers a 256B row span (L2 merge).
// ============================================================================
__global__ __launch_bounds__(256, 2) void k_main_mfma(const float* __restrict__ x,
                                                      const __bf16* __restrict__ WcT,
                                                      const float* __restrict__ biasc,
                                                      float* __restrict__ out) {
    __shared__ __align__(16) __bf16 Xs[64 * 256];   // 32 KB
    const int t = threadIdx.x;
    const int w = t >> 6;
    const int l = t & 63;
    const int l16 = l & 15, lq = l >> 4;
    const int nb = w * 64;
    const int swz = (l16 & 7) << 3;

    // ---- B fragments: preload all 4 ni x 8 kc (128 VGPRs), once per block.
    bf16x8 bfr[4][8];
#pragma unroll
    for (int ni = 0; ni < 4; ++ni) {
        const int n = nb + ni * 16 + l16;
#pragma unroll
        for (int kc = 0; kc < 8; ++kc)
            bfr[ni][kc] = *(const bf16x8*)(WcT + (size_t)n * 256 + kc * 32 + lq * 8);
    }

    // biasc for this wave's 4 col-groups (guarded; col>=250 unused later)
    float bc[4];
#pragma unroll
    for (int ni = 0; ni < 4; ++ni) {
        const int col = nb + ni * 16 + l16;
        bc[ni] = (col < ND) ? biasc[col] : 0.f;
    }

    for (int s = 0; s < 2; ++s) {
        const size_t m0 = (size_t)(blockIdx.x + s * 504) * 64;
        __syncthreads();   // protect Xs from previous tile's readers
        // ---- stage A: 64 rows x 32 octets; coalesced float2 global reads.
#pragma unroll
        for (int it = 0; it < 8; ++it) {
            const int u = it * 256 + t;
            const int row = u >> 5;
            const int ko = (u & 31) << 3;
            const float* src = x + (m0 + row) * NF + ko;
            float v[8];
#pragma unroll
            for (int q = 0; q < 4; ++q) {
                if (ko + 2 * q + 1 < NF) {
                    const float2 p = *(const float2*)(src + 2 * q);
                    v[2 * q] = p.x; v[2 * q + 1] = p.y;
                } else { v[2 * q] = 0.f; v[2 * q + 1] = 0.f; }
            }
            bf16x8 hv;
#pragma unroll
            for (int j = 0; j < 8; ++j) hv[j] = (__bf16)v[j];
            *(bf16x8*)&Xs[row * 256 + (ko ^ ((row & 7) << 3))] = hv;
        }
        __syncthreads();

        // ---- compute: acc[mi][ni] over 8 K-chunks, A from LDS, B from regs.
        f32x4 acc[4][4];
        const f32x4 z4 = {0.f, 0.f, 0.f, 0.f};
#pragma unroll
        for (int mi = 0; mi < 4; ++mi)
#pragma unroll
            for (int ni = 0; ni < 4; ++ni) acc[mi][ni] = z4;

#pragma unroll
        for (int kc = 0; kc < 8; ++kc) {
            const int kb = (kc * 32 + lq * 8) ^ swz;
            bf16x8 afr[4];
#pragma unroll
            for (int mi = 0; mi < 4; ++mi)
                afr[mi] = *(const bf16x8*)&Xs[(mi * 16 + l16) * 256 + kb];
#pragma unroll
            for (int mi = 0; mi < 4; ++mi)
#pragma unroll
                for (int ni = 0; ni < 4; ++ni)
                    acc[mi][ni] = __builtin_amdgcn_mfma_f32_16x16x32_bf16(
                        afr[mi], bfr[ni][kc], acc[mi][ni], 0, 0, 0);
        }

        // ---- store: (mi,r) outer, ni inner -> lane covers 256B row span.
#pragma unroll
        for (int mi = 0; mi < 4; ++mi) {
#pragma unroll
            for (int r = 0; r < 4; ++r) {
                const size_t row = m0 + mi * 16 + lq * 4 + r;
#pragma unroll
                for (int ni = 0; ni < 4; ++ni) {
                    const int col = nb + ni * 16 + l16;
                    if (col < ND)
                        out[row * ND + col] = acc[mi][ni][r] + bc[ni];
                }
            }
        }
    }
}

// ============================================================================
extern "C" void kernel_launch(void* const* d_in, const int* in_sizes, int n_in,
                              void* d_out, int out_size, void* d_ws, size_t ws_size,
                              hipStream_t stream) {
    const float* x       = (const float*)d_in[0];
    const float* Wg      = (const float*)d_in[1];
    const float* att_src = (const float*)d_in[2];
    const float* att_dst = (const float*)d_in[3];
    const float* bias_g  = (const float*)d_in[4];
    const float* Wp      = (const float*)d_in[5];
    const float* b_proj  = (const float*)d_in[6];
    float* out = (float*)d_out;
    float* ws  = (float*)d_ws;

    __bf16* WcT    = (__bf16*)ws;                 // 65536 bf16 = 32768 floats
    float* pWcT    = ws + 32768;                  // 8*65536 = 524288
    float* pbias   = pWcT + 8 * 65536;            // 2048
    float* biasc   = pbias + 2048;                // 256
    float* partial = biasc + 256;                 // 256*4096 = 1,048,576
    float* adj     = partial + 256 * 4096;        // 3969
    float* h0      = adj + NC * NC;               // 63,000
    float* as_     = h0 + NC * NHD;               // 252
    float* ad_     = as_ + NC * NH;               // 252
    float* wsm     = ad_ + NC * NH;               // 15,876  (total ~6.7 MB)

    k_wc_part<<<1008, 256, 0, stream>>>(Wg, bias_g, Wp, pWcT, pbias);
    k_wct<<<257, 256, 0, stream>>>(pWcT, pbias, b_proj, WcT, biasc);
    k_main_mfma<<<504, 256, 0, stream>>>(x, WcT, biasc, out);
    k_adj_mfma<<<256, 256, 0, stream>>>(x, partial);
    k_adj_reduce<<<63, 512, 0, stream>>>(partial, adj);
    k_h0asad<<<63, 256, 0, stream>>>(x, Wg, att_src, att_dst, h0, as_, ad_);
    k_mask_soft<<<1, 256, 0, stream>>>(adj, as_, ad_, wsm);
    k_out0<<<63, 512, 0, stream>>>(wsm, h0, bias_g, Wp, b_proj, out);
}

// Round 7
// 167.333 us; speedup vs baseline: 3.0165x; 1.2809x over previous
//
#include <hip/hip_runtime.h>
#include <math.h>

#define NB 1024
#define NC 63
#define NF 250
#define NH 4
#define ND 250
#define NHD 1000

typedef __bf16 bf16x8 __attribute__((ext_vector_type(8)));
typedef float f32x4 __attribute__((ext_vector_type(4)));

// ============================================================================
// k_adj_mfma: per-batch 64x64 gram via bf16 MFMA with hi/lo split (unchanged).
// ============================================================================
__global__ __launch_bounds__(256) void k_adj_mfma(const float* __restrict__ x,
                                                  float* __restrict__ partial) {
    __shared__ __align__(16) __bf16 Xh[64 * 256];   // 32 KB
    __shared__ __align__(16) __bf16 Xl[64 * 256];   // 32 KB
    __shared__ float sS[64], ssS[64], meanv[64], sclv[64];
    const int t = threadIdx.x;
    const int w = t >> 6, l = t & 63;
    const int l16 = l & 15, lq = l >> 4;
    const int swz = (l16 & 7) << 3;

    {
        const int kz = t ^ ((63 & 7) << 3);
        Xh[63 * 256 + kz] = (__bf16)1.0f;
        Xl[63 * 256 + kz] = (__bf16)0.0f;
    }

    float adjacc[4][4];
#pragma unroll
    for (int ni = 0; ni < 4; ++ni)
#pragma unroll
        for (int r = 0; r < 4; ++r) adjacc[ni][r] = 0.f;

    for (int bb = 0; bb < 4; ++bb) {
        const float* xb = x + (size_t)(blockIdx.x * 4 + bb) * (NC * NF);
#pragma unroll
        for (int it = 0; it < 8; ++it) {
            const int u = it * 256 + t;
            if (u < 2016) {
                const int row = u >> 5;
                const int ko = (u & 31) << 3;
                const float* src = xb + row * NF + ko;
                float v[8];
#pragma unroll
                for (int q = 0; q < 4; ++q) {
                    if (ko + q * 2 < NF) {
                        const float2 p = *(const float2*)(src + q * 2);
                        v[2 * q] = p.x; v[2 * q + 1] = p.y;
                    } else { v[2 * q] = 0.f; v[2 * q + 1] = 0.f; }
                }
                bf16x8 h, lo_;
#pragma unroll
                for (int j = 0; j < 8; ++j) {
                    h[j] = (__bf16)v[j];
                    lo_[j] = (__bf16)(v[j] - (float)h[j]);
                }
                const int kS = ko ^ ((row & 7) << 3);
                *(bf16x8*)&Xh[row * 256 + kS] = h;
                *(bf16x8*)&Xl[row * 256 + kS] = lo_;
            }
        }
        __syncthreads();

        f32x4 acc[4];
        const f32x4 z4 = {0.f, 0.f, 0.f, 0.f};
#pragma unroll
        for (int ni = 0; ni < 4; ++ni) acc[ni] = z4;
        const int arow = 16 * w + l16;
#pragma unroll
        for (int kc = 0; kc < 8; ++kc) {
            const int kb = (kc * 32 + lq * 8) ^ swz;
            const bf16x8 ah = *(const bf16x8*)&Xh[arow * 256 + kb];
            const bf16x8 al = *(const bf16x8*)&Xl[arow * 256 + kb];
#pragma unroll
            for (int ni = 0; ni < 4; ++ni) {
                const int brow = 16 * ni + l16;
                const bf16x8 bh = *(const bf16x8*)&Xh[brow * 256 + kb];
                const bf16x8 bl = *(const bf16x8*)&Xl[brow * 256 + kb];
                acc[ni] = __builtin_amdgcn_mfma_f32_16x16x32_bf16(ah, bh, acc[ni], 0, 0, 0);
                acc[ni] = __builtin_amdgcn_mfma_f32_16x16x32_bf16(ah, bl, acc[ni], 0, 0, 0);
                acc[ni] = __builtin_amdgcn_mfma_f32_16x16x32_bf16(al, bh, acc[ni], 0, 0, 0);
            }
        }

        if (l16 == 15) {
#pragma unroll
            for (int r = 0; r < 4; ++r) sS[16 * w + lq * 4 + r] = acc[3][r];
        }
        if ((l16 >> 2) == lq) ssS[16 * w + l16] = acc[w][l16 & 3];
        __syncthreads();
        if (t < 64) {
            const float S = sS[t], SSv = ssS[t];
            float m = S * (1.f / (float)NF);
            const float var = (SSv - S * S * (1.f / (float)NF)) * (1.f / (float)(NF - 1));
            float sc = 1.f / (sqrtf(var) + 1e-8f);
            if (t >= NC) { m = 0.f; sc = 0.f; }
            meanv[t] = m; sclv[t] = sc;
        }
        __syncthreads();

        float mr[4], sr[4];
#pragma unroll
        for (int r = 0; r < 4; ++r) {
            const int row = 16 * w + lq * 4 + r;
            mr[r] = meanv[row]; sr[r] = sclv[row];
        }
#pragma unroll
        for (int ni = 0; ni < 4; ++ni) {
            const float mc = meanv[16 * ni + l16];
            const float sc = sclv[16 * ni + l16];
#pragma unroll
            for (int r = 0; r < 4; ++r)
                adjacc[ni][r] += (acc[ni][r] - (float)NF * mr[r] * mc) * sr[r] * sc;
        }
    }

#pragma unroll
    for (int ni = 0; ni < 4; ++ni)
#pragma unroll
        for (int r = 0; r < 4; ++r) {
            const int row = 16 * w + lq * 4 + r;
            const int col = 16 * ni + l16;
            partial[(size_t)blockIdx.x * 4096 + row * 64 + col] = adjacc[ni][r];
        }
}

// ============================================================================
// Reduce 256 partials -> adj (63x63). grid 63 rows x 512 thr.
// ============================================================================
__global__ __launch_bounds__(512) void k_adj_reduce(const float* __restrict__ partial,
                                                    float* __restrict__ adj) {
    __shared__ float red[8][64];
    const int row = blockIdx.x, t = threadIdx.x;
    const int c = t & 63, g = t >> 6;
    float s = 0.f;
    const float* p = partial + (size_t)(g * 32) * 4096 + row * 64 + c;
#pragma unroll 8
    for (int i = 0; i < 32; ++i) s += p[(size_t)i * 4096];
    red[g][c] = s;
    __syncthreads();
    if (t < NC) {
        float tot = 0.f;
#pragma unroll
        for (int gg = 0; gg < 8; ++gg) tot += red[gg][t];
        adj[row * NC + t] = tot * (1.f / ((float)NF * (float)NB));
    }
}

// ============================================================================
// h0 = x[0] @ W_gat  (63 x 1000) + fused a_s/a_d per-head dots. grid 63.
// ============================================================================
__global__ __launch_bounds__(256) void k_h0asad(const float* __restrict__ x,
                                                const float* __restrict__ Wg,
                                                const float* __restrict__ att_src,
                                                const float* __restrict__ att_dst,
                                                float* __restrict__ h0,
                                                float* __restrict__ as_,
                                                float* __restrict__ ad_) {
    __shared__ float xrow[NF];
    __shared__ float y[NHD];
    __shared__ float red[256], red2[256];
    const int c = blockIdx.x, t = threadIdx.x;
    if (t < NF) xrow[t] = x[c * NF + t];
    __syncthreads();
    int n0 = t, n1 = t + 256, n2 = t + 512;
    int n3 = (t + 768 < NHD) ? t + 768 : NHD - 1;
    float acc0 = 0, acc1 = 0, acc2 = 0, acc3 = 0;
    for (int f = 0; f < NF; ++f) {
        float xv = xrow[f];
        const float* wr = Wg + (size_t)f * NHD;
        acc0 += xv * wr[n0];
        acc1 += xv * wr[n1];
        acc2 += xv * wr[n2];
        acc3 += xv * wr[n3];
    }
    h0[c * NHD + n0] = acc0; y[n0] = acc0;
    h0[c * NHD + n1] = acc1; y[n1] = acc1;
    h0[c * NHD + n2] = acc2; y[n2] = acc2;
    if (t + 768 < NHD) { h0[c * NHD + n3] = acc3; y[n3] = acc3; }
    __syncthreads();
    for (int h = 0; h < NH; ++h) {
        float vs = 0.f, vd = 0.f;
        if (t < ND) {
            float yv = y[h * ND + t];
            vs = yv * att_src[h * ND + t];
            vd = yv * att_dst[h * ND + t];
        }
        red[t] = vs; red2[t] = vd;
        __syncthreads();
        if (t < 128) { red[t] += red[t + 128]; red2[t] += red2[t + 128]; }
        __syncthreads();
        if (t < 64) { red[t] += red[t + 64]; red2[t] += red2[t + 64]; }
        __syncthreads();
        if (t < 64) {
            float r = red[t], r2 = red2[t];
#pragma unroll
            for (int off = 32; off >= 1; off >>= 1) {
                r += __shfl_down(r, off);
                r2 += __shfl_down(r2, off);
            }
            if (t == 0) { as_[c * NH + h] = r; ad_[c * NH + h] = r2; }
        }
        __syncthreads();
    }
}

// ============================================================================
// k_out0 v3: FUSED threshold + masked softmax + att0 + projection.
// grid 63 (j) x 512 thr. Replaces the 80us k_mask_soft latency-chain kernel:
//  - top-8 threshold: row values in LANES; <=8 iters of shfl_xor max-reduce
//    + __ballot/__popcll duplicate counting (all registers, no serial loads).
//    Recomputed per block (~1us) to enable the fusion.
//  - softmax for column j: wave h handles head h, lane i holds logit i;
//    shfl max/sum reduces. No serial LDS chains anywhere.
// ============================================================================
__global__ __launch_bounds__(512) void k_out0(const float* __restrict__ adj,
                                              const float* __restrict__ as_,
                                              const float* __restrict__ ad_,
                                              const float* __restrict__ h0,
                                              const float* __restrict__ bias_gat,
                                              const float* __restrict__ Wp,
                                              const float* __restrict__ b_proj,
                                              float* __restrict__ out) {
    __shared__ float adjS[NC * NC];
    __shared__ float thS[NC];
    __shared__ float asS[NC * 5];        // stride-5 pad (kills 8-way conflict)
    __shared__ float adS[NC * NH];
    __shared__ float wcol[NC * NH];
    __shared__ float y[NHD];
    __shared__ float psum[2][256];
    const int j = blockIdx.x, t = threadIdx.x;
    const int w = t >> 6, l = t & 63;

    for (int e = t; e < NC * NC; e += 512) adjS[e] = adj[e];
    if (t < NC * NH) { asS[(t >> 2) * 5 + (t & 3)] = as_[t]; adS[t] = ad_[t]; }
    __syncthreads();

    // ---- duplicate-aware top-8 threshold, rows r = w, w+8, ...
    for (int r = w; r < NC; r += 8) {
        const float v = (l < NC) ? adjS[r * NC + l] : -INFINITY;
        float prev = INFINITY;
        int krem = 8;                     // TOP_K
        float th = -INFINITY;
#pragma unroll
        for (int iter = 0; iter < 8; ++iter) {
            const float vm = (v < prev) ? v : -INFINITY;
            float m = vm;
#pragma unroll
            for (int off = 32; off >= 1; off >>= 1) m = fmaxf(m, __shfl_xor(m, off));
            const unsigned long long b = __ballot(vm == m);
            const int cnt = __popcll(b);
            if (cnt >= krem) { th = m; break; }
            krem -= cnt; prev = m;
        }
        if (l == 0) thS[r] = th;
    }
    __syncthreads();

    // ---- masked leaky-relu softmax over i for (j, h=w), waves 0..3
    if (w < NH) {
        const int h = w, i = l;
        const float adv = adS[j * NH + h];
        const float a = (i < NC) ? adjS[i * NC + j] : 0.f;
        const bool msk = (i < NC) && ((i == j) || ((a >= thS[i]) && (a != 0.f)));
        float e = 0.f;
        if (msk) { e = asS[i * 5 + h] + adv; e = e > 0.f ? e : 0.2f * e; }
        float m = msk ? e : -INFINITY;
#pragma unroll
        for (int off = 32; off >= 1; off >>= 1) m = fmaxf(m, __shfl_xor(m, off));
        const float p = msk ? __expf(e - m) : 0.f;
        float s = p;
#pragma unroll
        for (int off = 32; off >= 1; off >>= 1) s += __shfl_xor(s, off);
        if (i < NC) wcol[i * NH + h] = p / s;
    }
    __syncthreads();

    // ---- att0: y[n] = sum_i wcol[i,h(n)] * h0[i][n] + bias_gat[n]
    for (int n = t; n < NHD; n += 512) {
        const int h = n / ND;
        float acc = 0.f;
        for (int i = 0; i < NC; ++i)
            acc += wcol[i * NH + h] * h0[i * NHD + n];
        y[n] = acc + bias_gat[n];
    }
    __syncthreads();

    // ---- projection: out[j] = y @ Wp + b_proj (K split 2-way)
    const int q = t >> 8, col = t & 255;
    float acc = 0.f;
    if (col < ND) {
        for (int k = q * 500; k < q * 500 + 500; ++k)
            acc += y[k] * Wp[(size_t)k * ND + col];
    }
    psum[q][col] = acc;
    __syncthreads();
    if (t < ND) out[j * ND + t] = psum[0][t] + psum[1][t] + b_proj[t];
}

// ============================================================================
// Wc split-K x8 partials, stored TRANSPOSED pWcT[kq][n][256f].
// ============================================================================
__global__ __launch_bounds__(256) void k_wc_part(const float* __restrict__ Wg,
                                                 const float* __restrict__ bias_gat,
                                                 const float* __restrict__ Wp,
                                                 float* __restrict__ pWcT,
                                                 float* __restrict__ pbias) {
    __shared__ float rows[250];
    const int b = blockIdx.x, t = threadIdx.x;
    if (b < 1000) {
        const int fb = (b >> 3) * 2, kq = b & 7;
        if (t < 250)
            rows[t] = Wg[(size_t)(fb + t / 125) * NHD + kq * 125 + (t % 125)];
        __syncthreads();
        if (t < ND) {
            float a0 = 0.f, a1 = 0.f;
            const float* wp = Wp + (size_t)(kq * 125) * ND + t;
            for (int k = 0; k < 125; ++k) {
                float wv = wp[(size_t)k * ND];
                a0 += rows[k] * wv;
                a1 += rows[125 + k] * wv;
            }
            pWcT[(size_t)kq * 65536 + (size_t)t * 256 + fb] = a0;
            pWcT[(size_t)kq * 65536 + (size_t)t * 256 + fb + 1] = a1;
        }
    } else {
        const int kq = b - 1000;
        if (t < ND) {
            float acc = 0.f;
            for (int k = kq * 125; k < kq * 125 + 125; ++k)
                acc += bias_gat[k] * Wp[(size_t)k * ND + t];
            pbias[kq * 256 + t] = acc;
        }
    }
}

// ============================================================================
// Combine: WcT[n][f] bf16 (padded [256][256]); block 256 does biasc.
// ============================================================================
__global__ __launch_bounds__(256) void k_wct(const float* __restrict__ pWcT,
                                             const float* __restrict__ pbias,
                                             const float* __restrict__ b_proj,
                                             __bf16* __restrict__ WcT,
                                             float* __restrict__ biasc) {
    const int n = blockIdx.x, t = threadIdx.x;
    if (n < 256) {
        float v = 0.f;
        if (n < ND && t < NF) {
            size_t e = (size_t)n * 256 + t;
#pragma unroll
            for (int kq = 0; kq < 8; ++kq) v += pWcT[(size_t)kq * 65536 + e];
        }
        WcT[n * 256 + t] = (__bf16)v;
    } else {
        if (t < ND) {
            float v = 0.f;
#pragma unroll
            for (int kq = 0; kq < 8; ++kq) v += pbias[kq * 256 + t];
            biasc[t] = v + b_proj[t];
        }
    }
}

// ============================================================================
// MAIN v3: out = x @ Wc + biasc via bf16 MFMA (unchanged from R6).
// ============================================================================
__global__ __launch_bounds__(256, 2) void k_main_mfma(const float* __restrict__ x,
                                                      const __bf16* __restrict__ WcT,
                                                      const float* __restrict__ biasc,
                                                      float* __restrict__ out) {
    __shared__ __align__(16) __bf16 Xs[64 * 256];   // 32 KB
    const int t = threadIdx.x;
    const int w = t >> 6;
    const int l = t & 63;
    const int l16 = l & 15, lq = l >> 4;
    const int nb = w * 64;
    const int swz = (l16 & 7) << 3;

    bf16x8 bfr[4][8];
#pragma unroll
    for (int ni = 0; ni < 4; ++ni) {
        const int n = nb + ni * 16 + l16;
#pragma unroll
        for (int kc = 0; kc < 8; ++kc)
            bfr[ni][kc] = *(const bf16x8*)(WcT + (size_t)n * 256 + kc * 32 + lq * 8);
    }

    float bc[4];
#pragma unroll
    for (int ni = 0; ni < 4; ++ni) {
        const int col = nb + ni * 16 + l16;
        bc[ni] = (col < ND) ? biasc[col] : 0.f;
    }

    for (int s = 0; s < 2; ++s) {
        const size_t m0 = (size_t)(blockIdx.x + s * 504) * 64;
        __syncthreads();
#pragma unroll
        for (int it = 0; it < 8; ++it) {
            const int u = it * 256 + t;
            const int row = u >> 5;
            const int ko = (u & 31) << 3;
            const float* src = x + (m0 + row) * NF + ko;
            float v[8];
#pragma unroll
            for (int q = 0; q < 4; ++q) {
                if (ko + 2 * q + 1 < NF) {
                    const float2 p = *(const float2*)(src + 2 * q);
                    v[2 * q] = p.x; v[2 * q + 1] = p.y;
                } else { v[2 * q] = 0.f; v[2 * q + 1] = 0.f; }
            }
            bf16x8 hv;
#pragma unroll
            for (int j = 0; j < 8; ++j) hv[j] = (__bf16)v[j];
            *(bf16x8*)&Xs[row * 256 + (ko ^ ((row & 7) << 3))] = hv;
        }
        __syncthreads();

        f32x4 acc[4][4];
        const f32x4 z4 = {0.f, 0.f, 0.f, 0.f};
#pragma unroll
        for (int mi = 0; mi < 4; ++mi)
#pragma unroll
            for (int ni = 0; ni < 4; ++ni) acc[mi][ni] = z4;

#pragma unroll
        for (int kc = 0; kc < 8; ++kc) {
            const int kb = (kc * 32 + lq * 8) ^ swz;
            bf16x8 afr[4];
#pragma unroll
            for (int mi = 0; mi < 4; ++mi)
                afr[mi] = *(const bf16x8*)&Xs[(mi * 16 + l16) * 256 + kb];
#pragma unroll
            for (int mi = 0; mi < 4; ++mi)
#pragma unroll
                for (int ni = 0; ni < 4; ++ni)
                    acc[mi][ni] = __builtin_amdgcn_mfma_f32_16x16x32_bf16(
                        afr[mi], bfr[ni][kc], acc[mi][ni], 0, 0, 0);
        }

#pragma unroll
        for (int mi = 0; mi < 4; ++mi) {
#pragma unroll
            for (int r = 0; r < 4; ++r) {
                const size_t row = m0 + mi * 16 + lq * 4 + r;
#pragma unroll
                for (int ni = 0; ni < 4; ++ni) {
                    const int col = nb + ni * 16 + l16;
                    if (col < ND)
                        out[row * ND + col] = acc[mi][ni][r] + bc[ni];
                }
            }
        }
    }
}

// ============================================================================
extern "C" void kernel_launch(void* const* d_in, const int* in_sizes, int n_in,
                              void* d_out, int out_size, void* d_ws, size_t ws_size,
                              hipStream_t stream) {
    const float* x       = (const float*)d_in[0];
    const float* Wg      = (const float*)d_in[1];
    const float* att_src = (const float*)d_in[2];
    const float* att_dst = (const float*)d_in[3];
    const float* bias_g  = (const float*)d_in[4];
    const float* Wp      = (const float*)d_in[5];
    const float* b_proj  = (const float*)d_in[6];
    float* out = (float*)d_out;
    float* ws  = (float*)d_ws;

    __bf16* WcT    = (__bf16*)ws;                 // 65536 bf16 = 32768 floats
    float* pWcT    = ws + 32768;                  // 8*65536 = 524288
    float* pbias   = pWcT + 8 * 65536;            // 2048
    float* biasc   = pbias + 2048;                // 256
    float* partial = biasc + 256;                 // 256*4096 = 1,048,576
    float* adj     = partial + 256 * 4096;        // 3969
    float* h0      = adj + NC * NC;               // 63,000
    float* as_     = h0 + NC * NHD;               // 252
    float* ad_     = as_ + NC * NH;               // 252  (total ~6.6 MB)

    k_wc_part<<<1008, 256, 0, stream>>>(Wg, bias_g, Wp, pWcT, pbias);
    k_wct<<<257, 256, 0, stream>>>(pWcT, pbias, b_proj, WcT, biasc);
    k_main_mfma<<<504, 256, 0, stream>>>(x, WcT, biasc, out);
    k_adj_mfma<<<256, 256, 0, stream>>>(x, partial);
    k_adj_reduce<<<63, 512, 0, stream>>>(partial, adj);
    k_h0asad<<<63, 256, 0, stream>>>(x, Wg, att_src, att_dst, h0, as_, ad_);
    k_out0<<<63, 512, 0, stream>>>(adj, as_, ad_, h0, bias_g, Wp, b_proj, out);
}

// Round 8
// 140.509 us; speedup vs baseline: 3.5924x; 1.1909x over previous
//
#include <hip/hip_runtime.h>
#include <math.h>

#define NB 1024
#define NC 63
#define NF 250
#define NH 4
#define ND 250
#define NHD 1000

typedef __bf16 bf16x8 __attribute__((ext_vector_type(8)));
typedef float f32x4 __attribute__((ext_vector_type(4)));

// ============================================================================
// k_adj_mfma: per-batch 64x64 gram via bf16 MFMA with hi/lo split (unchanged).
// ============================================================================
__global__ __launch_bounds__(256) void k_adj_mfma(const float* __restrict__ x,
                                                  float* __restrict__ partial) {
    __shared__ __align__(16) __bf16 Xh[64 * 256];   // 32 KB
    __shared__ __align__(16) __bf16 Xl[64 * 256];   // 32 KB
    __shared__ float sS[64], ssS[64], meanv[64], sclv[64];
    const int t = threadIdx.x;
    const int w = t >> 6, l = t & 63;
    const int l16 = l & 15, lq = l >> 4;
    const int swz = (l16 & 7) << 3;

    {
        const int kz = t ^ ((63 & 7) << 3);
        Xh[63 * 256 + kz] = (__bf16)1.0f;
        Xl[63 * 256 + kz] = (__bf16)0.0f;
    }

    float adjacc[4][4];
#pragma unroll
    for (int ni = 0; ni < 4; ++ni)
#pragma unroll
        for (int r = 0; r < 4; ++r) adjacc[ni][r] = 0.f;

    for (int bb = 0; bb < 4; ++bb) {
        const float* xb = x + (size_t)(blockIdx.x * 4 + bb) * (NC * NF);
#pragma unroll
        for (int it = 0; it < 8; ++it) {
            const int u = it * 256 + t;
            if (u < 2016) {
                const int row = u >> 5;
                const int ko = (u & 31) << 3;
                const float* src = xb + row * NF + ko;
                float v[8];
#pragma unroll
                for (int q = 0; q < 4; ++q) {
                    if (ko + q * 2 < NF) {
                        const float2 p = *(const float2*)(src + q * 2);
                        v[2 * q] = p.x; v[2 * q + 1] = p.y;
                    } else { v[2 * q] = 0.f; v[2 * q + 1] = 0.f; }
                }
                bf16x8 h, lo_;
#pragma unroll
                for (int j = 0; j < 8; ++j) {
                    h[j] = (__bf16)v[j];
                    lo_[j] = (__bf16)(v[j] - (float)h[j]);
                }
                const int kS = ko ^ ((row & 7) << 3);
                *(bf16x8*)&Xh[row * 256 + kS] = h;
                *(bf16x8*)&Xl[row * 256 + kS] = lo_;
            }
        }
        __syncthreads();

        f32x4 acc[4];
        const f32x4 z4 = {0.f, 0.f, 0.f, 0.f};
#pragma unroll
        for (int ni = 0; ni < 4; ++ni) acc[ni] = z4;
        const int arow = 16 * w + l16;
#pragma unroll
        for (int kc = 0; kc < 8; ++kc) {
            const int kb = (kc * 32 + lq * 8) ^ swz;
            const bf16x8 ah = *(const bf16x8*)&Xh[arow * 256 + kb];
            const bf16x8 al = *(const bf16x8*)&Xl[arow * 256 + kb];
#pragma unroll
            for (int ni = 0; ni < 4; ++ni) {
                const int brow = 16 * ni + l16;
                const bf16x8 bh = *(const bf16x8*)&Xh[brow * 256 + kb];
                const bf16x8 bl = *(const bf16x8*)&Xl[brow * 256 + kb];
                acc[ni] = __builtin_amdgcn_mfma_f32_16x16x32_bf16(ah, bh, acc[ni], 0, 0, 0);
                acc[ni] = __builtin_amdgcn_mfma_f32_16x16x32_bf16(ah, bl, acc[ni], 0, 0, 0);
                acc[ni] = __builtin_amdgcn_mfma_f32_16x16x32_bf16(al, bh, acc[ni], 0, 0, 0);
            }
        }

        if (l16 == 15) {
#pragma unroll
            for (int r = 0; r < 4; ++r) sS[16 * w + lq * 4 + r] = acc[3][r];
        }
        if ((l16 >> 2) == lq) ssS[16 * w + l16] = acc[w][l16 & 3];
        __syncthreads();
        if (t < 64) {
            const float S = sS[t], SSv = ssS[t];
            float m = S * (1.f / (float)NF);
            const float var = (SSv - S * S * (1.f / (float)NF)) * (1.f / (float)(NF - 1));
            float sc = 1.f / (sqrtf(var) + 1e-8f);
            if (t >= NC) { m = 0.f; sc = 0.f; }
            meanv[t] = m; sclv[t] = sc;
        }
        __syncthreads();

        float mr[4], sr[4];
#pragma unroll
        for (int r = 0; r < 4; ++r) {
            const int row = 16 * w + lq * 4 + r;
            mr[r] = meanv[row]; sr[r] = sclv[row];
        }
#pragma unroll
        for (int ni = 0; ni < 4; ++ni) {
            const float mc = meanv[16 * ni + l16];
            const float sc = sclv[16 * ni + l16];
#pragma unroll
            for (int r = 0; r < 4; ++r)
                adjacc[ni][r] += (acc[ni][r] - (float)NF * mr[r] * mc) * sr[r] * sc;
        }
    }

#pragma unroll
    for (int ni = 0; ni < 4; ++ni)
#pragma unroll
        for (int r = 0; r < 4; ++r) {
            const int row = 16 * w + lq * 4 + r;
            const int col = 16 * ni + l16;
            partial[(size_t)blockIdx.x * 4096 + row * 64 + col] = adjacc[ni][r];
        }
}

// ============================================================================
// Reduce 256 partials -> adj (63x63). grid 63 rows x 512 thr. (unchanged)
// ============================================================================
__global__ __launch_bounds__(512) void k_adj_reduce(const float* __restrict__ partial,
                                                    float* __restrict__ adj) {
    __shared__ float red[8][64];
    const int row = blockIdx.x, t = threadIdx.x;
    const int c = t & 63, g = t >> 6;
    float s = 0.f;
    const float* p = partial + (size_t)(g * 32) * 4096 + row * 64 + c;
#pragma unroll 8
    for (int i = 0; i < 32; ++i) s += p[(size_t)i * 4096];
    red[g][c] = s;
    __syncthreads();
    if (t < NC) {
        float tot = 0.f;
#pragma unroll
        for (int gg = 0; gg < 8; ++gg) tot += red[gg][t];
        adj[row * NC + t] = tot * (1.f / ((float)NF * (float)NB));
    }
}

// ============================================================================
// k_gs: gs[f][h] = Wg[f, h-slice] . att_src[h],  gd likewise. grid 250 x 256.
// Replaces h0asad's Wg streaming (63 blocks x 4MB) with one parallel pass.
// ============================================================================
__global__ __launch_bounds__(256) void k_gs(const float* __restrict__ Wg,
                                            const float* __restrict__ att_src,
                                            const float* __restrict__ att_dst,
                                            float* __restrict__ gs,
                                            float* __restrict__ gd) {
    const int f = blockIdx.x;
    const int h = threadIdx.x >> 6, l = threadIdx.x & 63;
    const float* wr = Wg + (size_t)f * NHD + h * ND;
    const float* sp = att_src + h * ND;
    const float* dp = att_dst + h * ND;
    float s = 0.f, d = 0.f;
#pragma unroll
    for (int q = 0; q < 4; ++q) {
        const int dd = l + q * 64;
        if (dd < ND) {
            const float wv = wr[dd];
            s += wv * sp[dd];
            d += wv * dp[dd];
        }
    }
#pragma unroll
    for (int off = 32; off >= 1; off >>= 1) {
        s += __shfl_down(s, off);
        d += __shfl_down(d, off);
    }
    if (l == 0) { gs[f * NH + h] = s; gd[f * NH + h] = d; }
}

// ============================================================================
// k_asad: as[c,h] = x0[c] . gs[:,h]  (exact reorder of h0.att_src).
// One block, x0 (61.5KB) + gs/gd staged in LDS; thread = (c,h) pair.
// ============================================================================
__global__ __launch_bounds__(512) void k_asad(const float* __restrict__ x,
                                              const float* __restrict__ gs,
                                              const float* __restrict__ gd,
                                              float* __restrict__ as_,
                                              float* __restrict__ ad_) {
    __shared__ float x0S[NC * NF];       // 61.5 KB
    __shared__ float gsS[NF * NH], gdS[NF * NH];
    const int t = threadIdx.x;
    for (int e = t; e < NC * NF; e += 512) x0S[e] = x[e];
    for (int e = t; e < NF * NH; e += 512) { gsS[e] = gs[e]; gdS[e] = gd[e]; }
    __syncthreads();
    if (t < NC * NH) {
        const int c = t >> 2, h = t & 3;
        float s = 0.f, d = 0.f;
#pragma unroll 5
        for (int f = 0; f < NF; ++f) {
            const float xv = x0S[c * NF + f];
            s += xv * gsS[f * NH + h];
            d += xv * gdS[f * NH + h];
        }
        as_[t] = s; ad_[t] = d;
    }
}

// ============================================================================
// k_out0 v4: softmax (register, unchanged) + projection over hp (K=252).
// out0[j] = sum_{h,i} w[i,j,h] * hp[h*64+i] + biasc.  grid 63 x 512.
// Replaces the K=1000 per-j latency chain (60us) with 128 coalesced loads.
// ============================================================================
__global__ __launch_bounds__(512) void k_out0(const float* __restrict__ adj,
                                              const float* __restrict__ as_,
                                              const float* __restrict__ ad_,
                                              const float* __restrict__ hp,
                                              const float* __restrict__ biasc,
                                              float* __restrict__ out) {
    __shared__ float adjS[NC * NC];
    __shared__ float thS[NC];
    __shared__ float asS[NC * 5];        // stride-5 pad
    __shared__ float adS[NC * NH];
    __shared__ float wS[256];            // w[h*64+i], zeros at i=63
    __shared__ float psum[2][256];
    const int j = blockIdx.x, t = threadIdx.x;
    const int w = t >> 6, l = t & 63;

    for (int e = t; e < NC * NC; e += 512) adjS[e] = adj[e];
    if (t < NC * NH) { asS[(t >> 2) * 5 + (t & 3)] = as_[t]; adS[t] = ad_[t]; }
    __syncthreads();

    // ---- duplicate-aware top-8 threshold, rows r = w, w+8, ...
    for (int r = w; r < NC; r += 8) {
        const float v = (l < NC) ? adjS[r * NC + l] : -INFINITY;
        float prev = INFINITY;
        int krem = 8;                     // TOP_K
        float th = -INFINITY;
#pragma unroll
        for (int iter = 0; iter < 8; ++iter) {
            const float vm = (v < prev) ? v : -INFINITY;
            float m = vm;
#pragma unroll
            for (int off = 32; off >= 1; off >>= 1) m = fmaxf(m, __shfl_xor(m, off));
            const unsigned long long b = __ballot(vm == m);
            const int cnt = __popcll(b);
            if (cnt >= krem) { th = m; break; }
            krem -= cnt; prev = m;
        }
        if (l == 0) thS[r] = th;
    }
    __syncthreads();

    // ---- masked leaky-relu softmax over i for (j, h=w), waves 0..3
    if (w < NH) {
        const int h = w, i = l;
        const float adv = adS[j * NH + h];
        const float a = (i < NC) ? adjS[i * NC + j] : 0.f;
        const bool msk = (i < NC) && ((i == j) || ((a >= thS[i]) && (a != 0.f)));
        float e = 0.f;
        if (msk) { e = asS[i * 5 + h] + adv; e = e > 0.f ? e : 0.2f * e; }
        float m = msk ? e : -INFINITY;
#pragma unroll
        for (int off = 32; off >= 1; off >>= 1) m = fmaxf(m, __shfl_xor(m, off));
        const float p = msk ? __expf(e - m) : 0.f;
        float s = p;
#pragma unroll
        for (int off = 32; off >= 1; off >>= 1) s += __shfl_xor(s, off);
        wS[(h << 6) + l] = p / s;        // 0 for i=63 / unmasked
    }
    __syncthreads();

    // ---- projection over hp: K=256 (incl zero rows), 2-way split
    const int q = t >> 8, col = t & 255;
    float acc = 0.f;
    const float* hpc = hp + col;
#pragma unroll 8
    for (int e = q * 128; e < q * 128 + 128; ++e)
        acc += wS[e] * hpc[(size_t)e * 256];
    psum[q][col] = acc;
    __syncthreads();
    if (t < ND) out[(size_t)j * ND + t] = psum[0][t] + psum[1][t] + biasc[t];
}

// ============================================================================
// Wc split-K x8 partials, stored TRANSPOSED pWcT[kq][n][256f]. (unchanged)
// ============================================================================
__global__ __launch_bounds__(256) void k_wc_part(const float* __restrict__ Wg,
                                                 const float* __restrict__ bias_gat,
                                                 const float* __restrict__ Wp,
                                                 float* __restrict__ pWcT,
                                                 float* __restrict__ pbias) {
    __shared__ float rows[250];
    const int b = blockIdx.x, t = threadIdx.x;
    if (b < 1000) {
        const int fb = (b >> 3) * 2, kq = b & 7;
        if (t < 250)
            rows[t] = Wg[(size_t)(fb + t / 125) * NHD + kq * 125 + (t % 125)];
        __syncthreads();
        if (t < ND) {
            float a0 = 0.f, a1 = 0.f;
            const float* wp = Wp + (size_t)(kq * 125) * ND + t;
            for (int k = 0; k < 125; ++k) {
                float wv = wp[(size_t)k * ND];
                a0 += rows[k] * wv;
                a1 += rows[125 + k] * wv;
            }
            pWcT[(size_t)kq * 65536 + (size_t)t * 256 + fb] = a0;
            pWcT[(size_t)kq * 65536 + (size_t)t * 256 + fb + 1] = a1;
        }
    } else {
        const int kq = b - 1000;
        if (t < ND) {
            float acc = 0.f;
            for (int k = kq * 125; k < kq * 125 + 125; ++k)
                acc += bias_gat[k] * Wp[(size_t)k * ND + t];
            pbias[kq * 256 + t] = acc;
        }
    }
}

// ============================================================================
// Combine: WcT (= sum of 8) AND per-head WchT[h] (= pair sums) bf16;
// block 256 does biasc. kq pairs (2h, 2h+1) are exactly head h's K-slice.
// ============================================================================
__global__ __launch_bounds__(256) void k_wct(const float* __restrict__ pWcT,
                                             const float* __restrict__ pbias,
                                             const float* __restrict__ b_proj,
                                             __bf16* __restrict__ WcT,
                                             __bf16* __restrict__ WchT,
                                             float* __restrict__ biasc) {
    const int n = blockIdx.x, t = threadIdx.x;
    if (n < 256) {
        float v[8];
        float tot = 0.f;
#pragma unroll
        for (int kq = 0; kq < 8; ++kq) {
            float xv = 0.f;
            if (n < ND && t < NF) xv = pWcT[(size_t)kq * 65536 + (size_t)n * 256 + t];
            v[kq] = xv; tot += xv;
        }
        WcT[n * 256 + t] = (__bf16)tot;
#pragma unroll
        for (int h = 0; h < NH; ++h)
            WchT[h * 65536 + n * 256 + t] = (__bf16)(v[2 * h] + v[2 * h + 1]);
    } else {
        if (t < ND) {
            float v = 0.f;
#pragma unroll
            for (int kq = 0; kq < 8; ++kq) v += pbias[kq * 256 + t];
            biasc[t] = v + b_proj[t];
        }
    }
}

// ============================================================================
// k_hp: hp[h*64+i][col] = x0[i] @ Wch[h]  via MFMA (k_main clone, grid 4 = h).
// ============================================================================
__global__ __launch_bounds__(256) void k_hp(const float* __restrict__ x,
                                            const __bf16* __restrict__ WchT,
                                            float* __restrict__ hp) {
    __shared__ __align__(16) __bf16 Xs[64 * 256];
    const int h = blockIdx.x;
    const int t = threadIdx.x;
    const int w = t >> 6, l = t & 63;
    const int l16 = l & 15, lq = l >> 4;
    const int nb = w * 64;
    const int swz = (l16 & 7) << 3;

    bf16x8 bfr[4][8];
    const __bf16* Wh = WchT + h * 65536;
#pragma unroll
    for (int ni = 0; ni < 4; ++ni) {
        const int n = nb + ni * 16 + l16;
#pragma unroll
        for (int kc = 0; kc < 8; ++kc)
            bfr[ni][kc] = *(const bf16x8*)(Wh + (size_t)n * 256 + kc * 32 + lq * 8);
    }

    // stage x0 (rows 0..62, row 63 zero)
#pragma unroll
    for (int it = 0; it < 8; ++it) {
        const int u = it * 256 + t;
        const int row = u >> 5;
        const int ko = (u & 31) << 3;
        float v[8];
#pragma unroll
        for (int q = 0; q < 4; ++q) { v[2 * q] = 0.f; v[2 * q + 1] = 0.f; }
        if (row < NC) {
            const float* src = x + row * NF + ko;
#pragma unroll
            for (int q = 0; q < 4; ++q) {
                if (ko + 2 * q + 1 < NF) {
                    const float2 p = *(const float2*)(src + 2 * q);
                    v[2 * q] = p.x; v[2 * q + 1] = p.y;
                }
            }
        }
        bf16x8 hv;
#pragma unroll
        for (int jj = 0; jj < 8; ++jj) hv[jj] = (__bf16)v[jj];
        *(bf16x8*)&Xs[row * 256 + (ko ^ ((row & 7) << 3))] = hv;
    }
    __syncthreads();

    f32x4 acc[4][4];
    const f32x4 z4 = {0.f, 0.f, 0.f, 0.f};
#pragma unroll
    for (int mi = 0; mi < 4; ++mi)
#pragma unroll
        for (int ni = 0; ni < 4; ++ni) acc[mi][ni] = z4;

#pragma unroll
    for (int kc = 0; kc < 8; ++kc) {
        const int kb = (kc * 32 + lq * 8) ^ swz;
        bf16x8 afr[4];
#pragma unroll
        for (int mi = 0; mi < 4; ++mi)
            afr[mi] = *(const bf16x8*)&Xs[(mi * 16 + l16) * 256 + kb];
#pragma unroll
        for (int mi = 0; mi < 4; ++mi)
#pragma unroll
            for (int ni = 0; ni < 4; ++ni)
                acc[mi][ni] = __builtin_amdgcn_mfma_f32_16x16x32_bf16(
                    afr[mi], bfr[ni][kc], acc[mi][ni], 0, 0, 0);
    }

#pragma unroll
    for (int mi = 0; mi < 4; ++mi)
#pragma unroll
        for (int r = 0; r < 4; ++r) {
            const int row = mi * 16 + lq * 4 + r;
#pragma unroll
            for (int ni = 0; ni < 4; ++ni) {
                const int col = nb + ni * 16 + l16;
                hp[(size_t)(h * 64 + row) * 256 + col] = acc[mi][ni][r];
            }
        }
}

// ============================================================================
// MAIN v3: out = x @ Wc + biasc via bf16 MFMA (unchanged).
// ============================================================================
__global__ __launch_bounds__(256, 2) void k_main_mfma(const float* __restrict__ x,
                                                      const __bf16* __restrict__ WcT,
                                                      const float* __restrict__ biasc,
                                                      float* __restrict__ out) {
    __shared__ __align__(16) __bf16 Xs[64 * 256];   // 32 KB
    const int t = threadIdx.x;
    const int w = t >> 6;
    const int l = t & 63;
    const int l16 = l & 15, lq = l >> 4;
    const int nb = w * 64;
    const int swz = (l16 & 7) << 3;

    bf16x8 bfr[4][8];
#pragma unroll
    for (int ni = 0; ni < 4; ++ni) {
        const int n = nb + ni * 16 + l16;
#pragma unroll
        for (int kc = 0; kc < 8; ++kc)
            bfr[ni][kc] = *(const bf16x8*)(WcT + (size_t)n * 256 + kc * 32 + lq * 8);
    }

    float bc[4];
#pragma unroll
    for (int ni = 0; ni < 4; ++ni) {
        const int col = nb + ni * 16 + l16;
        bc[ni] = (col < ND) ? biasc[col] : 0.f;
    }

    for (int s = 0; s < 2; ++s) {
        const size_t m0 = (size_t)(blockIdx.x + s * 504) * 64;
        __syncthreads();
#pragma unroll
        for (int it = 0; it < 8; ++it) {
            const int u = it * 256 + t;
            const int row = u >> 5;
            const int ko = (u & 31) << 3;
            const float* src = x + (m0 + row) * NF + ko;
            float v[8];
#pragma unroll
            for (int q = 0; q < 4; ++q) {
                if (ko + 2 * q + 1 < NF) {
                    const float2 p = *(const float2*)(src + 2 * q);
                    v[2 * q] = p.x; v[2 * q + 1] = p.y;
                } else { v[2 * q] = 0.f; v[2 * q + 1] = 0.f; }
            }
            bf16x8 hv;
#pragma unroll
            for (int j = 0; j < 8; ++j) hv[j] = (__bf16)v[j];
            *(bf16x8*)&Xs[row * 256 + (ko ^ ((row & 7) << 3))] = hv;
        }
        __syncthreads();

        f32x4 acc[4][4];
        const f32x4 z4 = {0.f, 0.f, 0.f, 0.f};
#pragma unroll
        for (int mi = 0; mi < 4; ++mi)
#pragma unroll
            for (int ni = 0; ni < 4; ++ni) acc[mi][ni] = z4;

#pragma unroll
        for (int kc = 0; kc < 8; ++kc) {
            const int kb = (kc * 32 + lq * 8) ^ swz;
            bf16x8 afr[4];
#pragma unroll
            for (int mi = 0; mi < 4; ++mi)
                afr[mi] = *(const bf16x8*)&Xs[(mi * 16 + l16) * 256 + kb];
#pragma unroll
            for (int mi = 0; mi < 4; ++mi)
#pragma unroll
                for (int ni = 0; ni < 4; ++ni)
                    acc[mi][ni] = __builtin_amdgcn_mfma_f32_16x16x32_bf16(
                        afr[mi], bfr[ni][kc], acc[mi][ni], 0, 0, 0);
        }

#pragma unroll
        for (int mi = 0; mi < 4; ++mi) {
#pragma unroll
            for (int r = 0; r < 4; ++r) {
                const size_t row = m0 + mi * 16 + lq * 4 + r;
#pragma unroll
                for (int ni = 0; ni < 4; ++ni) {
                    const int col = nb + ni * 16 + l16;
                    if (col < ND)
                        out[row * ND + col] = acc[mi][ni][r] + bc[ni];
                }
            }
        }
    }
}

// ============================================================================
extern "C" void kernel_launch(void* const* d_in, const int* in_sizes, int n_in,
                              void* d_out, int out_size, void* d_ws, size_t ws_size,
                              hipStream_t stream) {
    const float* x       = (const float*)d_in[0];
    const float* Wg      = (const float*)d_in[1];
    const float* att_src = (const float*)d_in[2];
    const float* att_dst = (const float*)d_in[3];
    const float* bias_g  = (const float*)d_in[4];
    const float* Wp      = (const float*)d_in[5];
    const float* b_proj  = (const float*)d_in[6];
    float* out = (float*)d_out;
    float* ws  = (float*)d_ws;

    __bf16* WcT    = (__bf16*)ws;                 // 65536 bf16  = 32768 f
    __bf16* WchT   = (__bf16*)(ws + 32768);       // 4*65536 bf16 = 131072 f
    float* pWcT    = ws + 32768 + 131072;         // 8*65536 = 524288
    float* pbias   = pWcT + 8 * 65536;            // 2048
    float* biasc   = pbias + 2048;                // 256
    float* partial = biasc + 256;                 // 256*4096 = 1,048,576
    float* adj     = partial + 256 * 4096;        // 3969
    float* hp      = adj + NC * NC;               // 256*256 = 65536
    float* gs      = hp + 65536;                  // 1000
    float* gd      = gs + 1000;                   // 1000
    float* as_     = gd + 1000;                   // 252
    float* ad_     = as_ + 252;                   // 252  (total ~7.2 MB)

    k_wc_part<<<1008, 256, 0, stream>>>(Wg, bias_g, Wp, pWcT, pbias);
    k_wct<<<257, 256, 0, stream>>>(pWcT, pbias, b_proj, WcT, WchT, biasc);
    k_main_mfma<<<504, 256, 0, stream>>>(x, WcT, biasc, out);
    k_hp<<<4, 256, 0, stream>>>(x, WchT, hp);
    k_adj_mfma<<<256, 256, 0, stream>>>(x, partial);
    k_adj_reduce<<<63, 512, 0, stream>>>(partial, adj);
    k_gs<<<250, 256, 0, stream>>>(Wg, att_src, att_dst, gs, gd);
    k_asad<<<1, 512, 0, stream>>>(x, gs, gd, as_, ad_);
    k_out0<<<63, 512, 0, stream>>>(adj, as_, ad_, hp, biasc, out);
}